// Round 5
// baseline (5706.082 us; speedup 1.0000x reference)
//
#include <hip/hip_runtime.h>
#include <math.h>

#define TT 9

typedef __attribute__((ext_vector_type(8))) short bf16x8;
typedef __attribute__((ext_vector_type(4))) float f32x4;

__device__ __forceinline__ unsigned short f2bf(float x) {
    unsigned int u = __float_as_uint(x);
    unsigned int r = (u + 0x7fffu + ((u >> 16) & 1u)) >> 16;
    return (unsigned short)r;
}
__device__ __forceinline__ float bf2f(unsigned short h) {
    return __uint_as_float((unsigned int)h << 16);
}

// ============================================================================
// cvtA: A fp32 [rows,K] -> Ah,Al bf16 [rows,Kp] (zero-padded K..Kp)
// grid (rows, ceil(Kp/256)), block 256
// ============================================================================
__global__ __launch_bounds__(256) void cvta_kernel(
    const float* __restrict__ A, unsigned short* __restrict__ Ah,
    unsigned short* __restrict__ Al, int K, int Kp)
{
    const int row = blockIdx.x;
    const int k = blockIdx.y * 256 + threadIdx.x;
    if (k >= Kp) return;
    float v = (k < K) ? A[(size_t)row * K + k] : 0.f;
    unsigned short h = f2bf(v);
    unsigned short l = f2bf(v - bf2f(h));
    Ah[(size_t)row * Kp + k] = h;
    Al[(size_t)row * Kp + k] = l;
}

// ============================================================================
// cvtW: W fp32 [K,768] -> Wth,Wtl bf16 [768,Kp] TRANSPOSED (zero-padded)
// grid (3, Kp), block 256
// ============================================================================
__global__ __launch_bounds__(256) void cvtw_kernel(
    const float* __restrict__ W, unsigned short* __restrict__ Wth,
    unsigned short* __restrict__ Wtl, int K, int Kp)
{
    const int n = blockIdx.x * 256 + threadIdx.x;
    const int k = blockIdx.y;
    if (n >= 768) return;
    float v = (k < K) ? W[(size_t)k * 768 + n] : 0.f;
    unsigned short h = f2bf(v);
    unsigned short l = f2bf(v - bf2f(h));
    Wth[(size_t)n * Kp + k] = h;
    Wtl[(size_t)n * Kp + k] = l;
}

// ============================================================================
// projm: C[M,768] = A@W + b via split-bf16 MFMA (Ah*Wh + Ah*Wl + Al*Wh).
// A as hi/lo bf16 [M,Kp]; W as hi/lo bf16 [768,Kp] transposed.
// 128x128 tile, BK=32, 256 threads = 4 waves (2x2), each wave 64x64 via
// 4x4 frags of mfma_f32_16x16x32_bf16. LDS rows padded to 40 shorts (80B =
// 20-bank stride -> <=2-way conflicts). Reg-staged, next-tile loads issued
// before the MFMA cluster.
// ============================================================================
__global__ __launch_bounds__(256) void projm_kernel(
    const unsigned short* __restrict__ Ah, const unsigned short* __restrict__ Al,
    const unsigned short* __restrict__ Wh, const unsigned short* __restrict__ Wl,
    const float* __restrict__ bs, float* __restrict__ C, int Kp)
{
    __shared__ unsigned short Ah_s[128][40];
    __shared__ unsigned short Al_s[128][40];
    __shared__ unsigned short Wh_s[128][40];
    __shared__ unsigned short Wl_s[128][40];

    const int tid = threadIdx.x;
    const int m0 = blockIdx.y * 128;
    const int n0 = blockIdx.x * 128;

    const int srow = tid >> 1;           // staging row 0..127
    const int skh  = (tid & 1) * 16;     // staging k-offset 0/16

    const unsigned short* pAh = Ah + (size_t)(m0 + srow) * Kp + skh;
    const unsigned short* pAl = Al + (size_t)(m0 + srow) * Kp + skh;
    const unsigned short* pWh = Wh + (size_t)(n0 + srow) * Kp + skh;
    const unsigned short* pWl = Wl + (size_t)(n0 + srow) * Kp + skh;

    const int w    = tid >> 6;
    const int wr   = (w >> 1) * 64;
    const int wc   = (w & 1) * 64;
    const int lane = tid & 63;
    const int lrow = lane & 15;
    const int kg8  = (lane >> 4) * 8;

    f32x4 acc[4][4];
    #pragma unroll
    for (int m = 0; m < 4; ++m)
        #pragma unroll
        for (int n = 0; n < 4; ++n)
            acc[m][n] = (f32x4){0.f, 0.f, 0.f, 0.f};

    // prologue loads (step 0)
    uint4 rAh0 = *(const uint4*)(pAh), rAh1 = *(const uint4*)(pAh + 8);
    uint4 rAl0 = *(const uint4*)(pAl), rAl1 = *(const uint4*)(pAl + 8);
    uint4 rWh0 = *(const uint4*)(pWh), rWh1 = *(const uint4*)(pWh + 8);
    uint4 rWl0 = *(const uint4*)(pWl), rWl1 = *(const uint4*)(pWl + 8);
    pAh += 32; pAl += 32; pWh += 32; pWl += 32;

    const int nsteps = Kp >> 5;
    for (int s = 0; s < nsteps; ++s) {
        __syncthreads();   // prior step's readers done
        *(uint4*)&Ah_s[srow][skh]     = rAh0;
        *(uint4*)&Ah_s[srow][skh + 8] = rAh1;
        *(uint4*)&Al_s[srow][skh]     = rAl0;
        *(uint4*)&Al_s[srow][skh + 8] = rAl1;
        *(uint4*)&Wh_s[srow][skh]     = rWh0;
        *(uint4*)&Wh_s[srow][skh + 8] = rWh1;
        *(uint4*)&Wl_s[srow][skh]     = rWl0;
        *(uint4*)&Wl_s[srow][skh + 8] = rWl1;
        __syncthreads();   // LDS ready

        if (s + 1 < nsteps) {   // issue next-step loads; latency hides under MFMA
            rAh0 = *(const uint4*)(pAh); rAh1 = *(const uint4*)(pAh + 8);
            rAl0 = *(const uint4*)(pAl); rAl1 = *(const uint4*)(pAl + 8);
            rWh0 = *(const uint4*)(pWh); rWh1 = *(const uint4*)(pWh + 8);
            rWl0 = *(const uint4*)(pWl); rWl1 = *(const uint4*)(pWl + 8);
            pAh += 32; pAl += 32; pWh += 32; pWl += 32;
        }

        bf16x8 fa_h[4], fa_l[4], fb_h[4], fb_l[4];
        #pragma unroll
        for (int m = 0; m < 4; ++m) {
            fa_h[m] = *(const bf16x8*)&Ah_s[wr + m * 16 + lrow][kg8];
            fa_l[m] = *(const bf16x8*)&Al_s[wr + m * 16 + lrow][kg8];
        }
        #pragma unroll
        for (int n = 0; n < 4; ++n) {
            fb_h[n] = *(const bf16x8*)&Wh_s[wc + n * 16 + lrow][kg8];
            fb_l[n] = *(const bf16x8*)&Wl_s[wc + n * 16 + lrow][kg8];
        }
        #pragma unroll
        for (int m = 0; m < 4; ++m)
            #pragma unroll
            for (int n = 0; n < 4; ++n) {
                acc[m][n] = __builtin_amdgcn_mfma_f32_16x16x32_bf16(fa_h[m], fb_h[n], acc[m][n], 0, 0, 0);
                acc[m][n] = __builtin_amdgcn_mfma_f32_16x16x32_bf16(fa_h[m], fb_l[n], acc[m][n], 0, 0, 0);
                acc[m][n] = __builtin_amdgcn_mfma_f32_16x16x32_bf16(fa_l[m], fb_h[n], acc[m][n], 0, 0, 0);
            }
    }

    // epilogue: C/D mapping col=lane&15, row=(lane>>4)*4+reg (m89-verified)
    const int orow = (lane >> 4) * 4;
    const int ocol = lane & 15;
    #pragma unroll
    for (int n = 0; n < 4; ++n) {
        const int col = n0 + wc + n * 16 + ocol;
        const float bn = bs[col];
        #pragma unroll
        for (int m = 0; m < 4; ++m) {
            const int rbase = m0 + wr + m * 16 + orow;
            #pragma unroll
            for (int r = 0; r < 4; ++r)
                C[(size_t)(rbase + r) * 768 + col] = acc[m][n][r] + bn;
        }
    }
}

// ============================================================================
// GRU: persistent-h kernel, ONE direction per launch (unchanged from r4).
// ============================================================================
__global__ __launch_bounds__(256) void gru_kernel(
    const float* __restrict__ xp, const float* __restrict__ U, const float* __restrict__ b,
    const float* __restrict__ h0, float* __restrict__ y, int out_off, int dir)
{
    const float* bi = b + 768;

    __shared__ float h[16][256];
    const int tid = threadIdx.x;
    const int r0 = blockIdx.x * 16;

    #pragma unroll
    for (int i = 0; i < 16; ++i)
        h[i][tid] = h0 ? h0[(size_t)(r0 + i) * 256 + tid] : 0.f;

    const float bz = bi[tid], br = bi[tid + 256], bh = bi[tid + 512];
    __syncthreads();

    for (int t = 0; t < TT; ++t) {
        const int te = dir ? (TT - 1 - t) : t;
        float acc0[16], acc1[16], acc2[16];
        #pragma unroll
        for (int i = 0; i < 16; ++i) { acc0[i] = 0.f; acc1[i] = 0.f; acc2[i] = 0.f; }

        for (int k = 0; k < 256; k += 8) {
            float w[8][3];
            #pragma unroll
            for (int kk = 0; kk < 8; ++kk) {
                const float* Ur = U + (size_t)(k + kk) * 768;
                w[kk][0] = Ur[tid];
                w[kk][1] = Ur[tid + 256];
                w[kk][2] = Ur[tid + 512];
            }
            #pragma unroll
            for (int i = 0; i < 16; ++i) {
                float4 hv0 = *(const float4*)&h[i][k];
                float4 hv1 = *(const float4*)&h[i][k + 4];
                float hvv[8] = {hv0.x, hv0.y, hv0.z, hv0.w, hv1.x, hv1.y, hv1.z, hv1.w};
                float s0 = acc0[i], s1 = acc1[i], s2 = acc2[i];
                #pragma unroll
                for (int kk = 0; kk < 8; ++kk) {
                    s0 = fmaf(hvv[kk], w[kk][0], s0);
                    s1 = fmaf(hvv[kk], w[kk][1], s1);
                    s2 = fmaf(hvv[kk], w[kk][2], s2);
                }
                acc0[i] = s0; acc1[i] = s1; acc2[i] = s2;
            }
        }
        __syncthreads();
        #pragma unroll
        for (int i = 0; i < 16; ++i) {
            const size_t xb = ((size_t)(r0 + i) * TT + te) * 768;
            float xz = xp[xb + tid];
            float xr = xp[xb + tid + 256];
            float xh = xp[xb + tid + 512];
            float z  = 1.f / (1.f + expf(-(xz + acc0[i] + bz)));
            float r  = 1.f / (1.f + expf(-(xr + acc1[i] + br)));
            float hh = tanhf(xh + r * (acc2[i] + bh));
            float hold = h[i][tid];
            float hn = z * hold + (1.f - z) * hh;
            h[i][tid] = hn;
            y[((size_t)(r0 + i) * TT + te) * 512 + out_off + tid] = hn;
        }
        __syncthreads();
    }
}

// ============================================================================
// score / softmax+ctx / fc (unchanged from r4)
// ============================================================================
__global__ __launch_bounds__(256) void score_kernel(
    const float* __restrict__ Y, const float* __restrict__ W1, const float* __restrict__ b1,
    const float* __restrict__ V, const float* __restrict__ bV,
    float* __restrict__ score)
{
    __shared__ float ylds[16][512];
    __shared__ float sred[16][256];
    const int tid = threadIdx.x;
    const int r0 = blockIdx.x * 16;

    for (int idx = tid; idx < 16 * 512; idx += 256)
        ylds[idx >> 9][idx & 511] = Y[(size_t)r0 * 512 + idx];
    __syncthreads();

    float acc0[16], acc1[16];
    #pragma unroll
    for (int i = 0; i < 16; ++i) { acc0[i] = 0.f; acc1[i] = 0.f; }

    for (int k = 0; k < 512; k += 8) {
        float w[8][2];
        #pragma unroll
        for (int kk = 0; kk < 8; ++kk) {
            const float* Wr = W1 + (size_t)(k + kk) * 512;
            w[kk][0] = Wr[tid];
            w[kk][1] = Wr[tid + 256];
        }
        #pragma unroll
        for (int i = 0; i < 16; ++i) {
            float4 y0 = *(const float4*)&ylds[i][k];
            float4 y1 = *(const float4*)&ylds[i][k + 4];
            float yv[8] = {y0.x, y0.y, y0.z, y0.w, y1.x, y1.y, y1.z, y1.w};
            float s0 = acc0[i], s1 = acc1[i];
            #pragma unroll
            for (int kk = 0; kk < 8; ++kk) {
                s0 = fmaf(yv[kk], w[kk][0], s0);
                s1 = fmaf(yv[kk], w[kk][1], s1);
            }
            acc0[i] = s0; acc1[i] = s1;
        }
    }
    const float v0 = V[tid], v1 = V[tid + 256];
    const float c0 = b1[tid], c1 = b1[tid + 256];
    #pragma unroll
    for (int i = 0; i < 16; ++i)
        sred[i][tid] = tanhf(acc0[i] + c0) * v0 + tanhf(acc1[i] + c1) * v1;
    __syncthreads();
    const int wave = tid >> 6, lane = tid & 63;
    for (int i = wave * 4; i < wave * 4 + 4; ++i) {
        float s = sred[i][lane] + sred[i][lane + 64] + sred[i][lane + 128] + sred[i][lane + 192];
        #pragma unroll
        for (int off = 32; off > 0; off >>= 1) s += __shfl_down(s, off);
        if (lane == 0) score[r0 + i] = s + bV[0];
    }
}

__global__ __launch_bounds__(64) void softmax_ctx_kernel(
    const float* __restrict__ score, const float* __restrict__ Y,
    float* __restrict__ ctx, float* __restrict__ att)
{
    const int b = blockIdx.x;
    const int lane = threadIdx.x;
    __shared__ float wv[TT];
    float s = (lane < TT) ? score[(size_t)b * TT + lane] : -3.0e38f;
    float m = s;
    #pragma unroll
    for (int off = 32; off > 0; off >>= 1) m = fmaxf(m, __shfl_xor(m, off));
    float e = (lane < TT) ? expf(s - m) : 0.f;
    float sum = e;
    #pragma unroll
    for (int off = 32; off > 0; off >>= 1) sum += __shfl_xor(sum, off);
    float wgt = e / sum;
    if (lane < TT) { att[(size_t)b * TT + lane] = wgt; wv[lane] = wgt; }
    __syncthreads();
    float wr[TT];
    #pragma unroll
    for (int t2 = 0; t2 < TT; ++t2) wr[t2] = wv[t2];
    #pragma unroll
    for (int j = 0; j < 8; ++j) {
        int c = lane + j * 64;
        float a = 0.f;
        #pragma unroll
        for (int t2 = 0; t2 < TT; ++t2)
            a = fmaf(wr[t2], Y[((size_t)b * TT + t2) * 512 + c], a);
        ctx[(size_t)b * 512 + c] = a;
    }
}

__global__ __launch_bounds__(256) void fc_kernel(
    const float* __restrict__ ctx, const float* __restrict__ W1, const float* __restrict__ b1,
    const float* __restrict__ W2, const float* __restrict__ b2,
    float* __restrict__ logits)
{
    __shared__ float clds[16][512];
    const int tid = threadIdx.x;
    const int r0 = blockIdx.x * 16;
    for (int idx = tid; idx < 16 * 512; idx += 256)
        clds[idx >> 9][idx & 511] = ctx[(size_t)r0 * 512 + idx];
    __syncthreads();

    float acc0[16], acc1[16];
    #pragma unroll
    for (int i = 0; i < 16; ++i) { acc0[i] = 0.f; acc1[i] = 0.f; }

    for (int k = 0; k < 512; k += 8) {
        float w[8][2];
        #pragma unroll
        for (int kk = 0; kk < 8; ++kk) {
            const float* Wr = W1 + (size_t)(k + kk) * 512;
            w[kk][0] = Wr[tid];
            w[kk][1] = Wr[tid + 256];
        }
        #pragma unroll
        for (int i = 0; i < 16; ++i) {
            float4 y0 = *(const float4*)&clds[i][k];
            float4 y1 = *(const float4*)&clds[i][k + 4];
            float yv[8] = {y0.x, y0.y, y0.z, y0.w, y1.x, y1.y, y1.z, y1.w};
            float s0 = acc0[i], s1 = acc1[i];
            #pragma unroll
            for (int kk = 0; kk < 8; ++kk) {
                s0 = fmaf(yv[kk], w[kk][0], s0);
                s1 = fmaf(yv[kk], w[kk][1], s1);
            }
            acc0[i] = s0; acc1[i] = s1;
        }
    }
    const float w2a0 = W2[(size_t)tid * 2],         w2a1 = W2[(size_t)tid * 2 + 1];
    const float w2b0 = W2[(size_t)(tid + 256) * 2], w2b1 = W2[(size_t)(tid + 256) * 2 + 1];
    const float c0 = b1[tid], c1 = b1[tid + 256];
    __syncthreads();
    #pragma unroll
    for (int i = 0; i < 16; ++i) {
        float h0 = fmaxf(acc0[i] + c0, 0.f);
        float h1 = fmaxf(acc1[i] + c1, 0.f);
        clds[i][tid * 2]     = fmaf(h0, w2a0, h1 * w2b0);
        clds[i][tid * 2 + 1] = fmaf(h0, w2a1, h1 * w2b1);
    }
    __syncthreads();
    const int wave = tid >> 6, lane = tid & 63;
    for (int i = wave * 4; i < wave * 4 + 4; ++i) {
        float px = clds[i][lane * 2]     + clds[i][(lane + 64) * 2]     + clds[i][(lane + 128) * 2]     + clds[i][(lane + 192) * 2];
        float py = clds[i][lane * 2 + 1] + clds[i][(lane + 64) * 2 + 1] + clds[i][(lane + 128) * 2 + 1] + clds[i][(lane + 192) * 2 + 1];
        #pragma unroll
        for (int off = 32; off > 0; off >>= 1) { px += __shfl_down(px, off); py += __shfl_down(py, off); }
        if (lane == 0) {
            logits[(size_t)(r0 + i) * 2]     = px + b2[0];
            logits[(size_t)(r0 + i) * 2 + 1] = py + b2[1];
        }
    }
}

// ============================================================================
extern "C" void kernel_launch(void* const* d_in, const int* in_sizes, int n_in,
                              void* d_out, int out_size, void* d_ws, size_t ws_size,
                              hipStream_t stream)
{
    const float* peptide = (const float*)d_in[0];
    const float* hidden  = (const float*)d_in[1];
    const float* gW[6] = { (const float*)d_in[2],  (const float*)d_in[5],
                           (const float*)d_in[8],  (const float*)d_in[11],
                           (const float*)d_in[14], (const float*)d_in[17] };
    const float* gU[6] = { (const float*)d_in[3],  (const float*)d_in[6],
                           (const float*)d_in[9],  (const float*)d_in[12],
                           (const float*)d_in[15], (const float*)d_in[18] };
    const float* gB[6] = { (const float*)d_in[4],  (const float*)d_in[7],
                           (const float*)d_in[10], (const float*)d_in[13],
                           (const float*)d_in[16], (const float*)d_in[19] };
    const float* att_W1 = (const float*)d_in[20];
    const float* att_b1 = (const float*)d_in[21];
    const float* att_V  = (const float*)d_in[22];
    const float* att_bV = (const float*)d_in[23];
    const float* fc1_W = (const float*)d_in[24];
    const float* fc1_b = (const float*)d_in[25];
    const float* fc2_W = (const float*)d_in[26];
    const float* fc2_b = (const float*)d_in[27];

    float* out = (float*)d_out;   // [0,8192) logits, [8192,45056) attention weights

    // Pick batch-chunk count so the workspace fits. Per chunk (bytes):
    //   xp [CB*9,768] f32 + yA,yB [CB*9,512] f32
    //   + Ah,Al [CB*9,576] bf16 + Wth,Wtl [768,576] bf16
    int NC = 1;
    size_t CB = 4096;
    for (; NC <= 32; NC *= 2) {
        CB = 4096 / NC;
        size_t bytes = (size_t)CB * TT * 768 * 4 + 2 * (size_t)CB * TT * 512 * 4
                     + 2 * (size_t)CB * TT * 576 * 2 + 2 * (size_t)768 * 576 * 2;
        if (bytes <= ws_size) break;
    }
    if (NC > 32) { NC = 32; CB = 128; }

    float* ws = (float*)d_ws;
    float* xp = ws;                                   // [CB*9, 768] f32
    float* yA = xp + (size_t)CB * TT * 768;           // [CB*9, 512] f32
    float* yB = yA + (size_t)CB * TT * 512;
    unsigned short* Ah  = (unsigned short*)(yB + (size_t)CB * TT * 512);
    unsigned short* Al  = Ah + (size_t)CB * TT * 576;
    unsigned short* Wth = Al + (size_t)CB * TT * 576;
    unsigned short* Wtl = Wth + (size_t)768 * 576;
    // score/ctx reuse the xp region (dead after the last gru):
    float* score = xp;
    float* ctx   = xp + (((size_t)CB * TT + 255) & ~(size_t)255);

    const int M = (int)CB * TT;                 // rows per chunk
    dim3 pb(256), pg(6, M / 128);               // projm: N/128 x M/128
    dim3 gb(256), gg((unsigned)CB / 16);        // gru: CB/16
    dim3 cab(256);

    for (int c = 0; c < NC; ++c) {
        const float* pep_c = peptide + (size_t)c * CB * TT * 553;
        const float* hid_c = hidden + (size_t)c * CB * 256;
        float* logits_c = out + (size_t)c * CB * 2;
        float* att_c    = out + 8192 + (size_t)c * CB * TT;

        // ---- layer 1 (K=553 -> Kp=576, h0 = hidden, both dirs share A) ----
        cvta_kernel<<<dim3((unsigned)M, 3), cab, 0, stream>>>(pep_c, Ah, Al, 553, 576);
        cvtw_kernel<<<dim3(3, 576), cab, 0, stream>>>(gW[0], Wth, Wtl, 553, 576);
        projm_kernel<<<pg, pb, 0, stream>>>(Ah, Al, Wth, Wtl, gB[0], xp, 576);
        gru_kernel<<<gg, gb, 0, stream>>>(xp, gU[0], gB[0], hid_c, yA, 0, 0);
        cvtw_kernel<<<dim3(3, 576), cab, 0, stream>>>(gW[1], Wth, Wtl, 553, 576);
        projm_kernel<<<pg, pb, 0, stream>>>(Ah, Al, Wth, Wtl, gB[1], xp, 576);
        gru_kernel<<<gg, gb, 0, stream>>>(xp, gU[1], gB[1], hid_c, yA, 256, 1);

        // ---- layer 2 (K=512, h0 = 0) ----
        cvta_kernel<<<dim3((unsigned)M, 2), cab, 0, stream>>>(yA, Ah, Al, 512, 512);
        cvtw_kernel<<<dim3(3, 512), cab, 0, stream>>>(gW[2], Wth, Wtl, 512, 512);
        projm_kernel<<<pg, pb, 0, stream>>>(Ah, Al, Wth, Wtl, gB[2], xp, 512);
        gru_kernel<<<gg, gb, 0, stream>>>(xp, gU[2], gB[2], nullptr, yB, 0, 0);
        cvtw_kernel<<<dim3(3, 512), cab, 0, stream>>>(gW[3], Wth, Wtl, 512, 512);
        projm_kernel<<<pg, pb, 0, stream>>>(Ah, Al, Wth, Wtl, gB[3], xp, 512);
        gru_kernel<<<gg, gb, 0, stream>>>(xp, gU[3], gB[3], nullptr, yB, 256, 1);

        // ---- layer 3 ----
        cvta_kernel<<<dim3((unsigned)M, 2), cab, 0, stream>>>(yB, Ah, Al, 512, 512);
        cvtw_kernel<<<dim3(3, 512), cab, 0, stream>>>(gW[4], Wth, Wtl, 512, 512);
        projm_kernel<<<pg, pb, 0, stream>>>(Ah, Al, Wth, Wtl, gB[4], xp, 512);
        gru_kernel<<<gg, gb, 0, stream>>>(xp, gU[4], gB[4], nullptr, yA, 0, 0);
        cvtw_kernel<<<dim3(3, 512), cab, 0, stream>>>(gW[5], Wth, Wtl, 512, 512);
        projm_kernel<<<pg, pb, 0, stream>>>(Ah, Al, Wth, Wtl, gB[5], xp, 512);
        gru_kernel<<<gg, gb, 0, stream>>>(xp, gU[5], gB[5], nullptr, yA, 256, 1);

        // ---- attention + head ----
        score_kernel<<<dim3(M / 16), dim3(256), 0, stream>>>(yA, att_W1, att_b1, att_V, att_bV, score);
        softmax_ctx_kernel<<<dim3((unsigned)CB), dim3(64), 0, stream>>>(score, yA, ctx, att_c);
        fc_kernel<<<dim3((unsigned)CB / 16), dim3(256), 0, stream>>>(ctx, fc1_W, fc1_b, fc2_W, fc2_b, logits_c);
    }
}

// Round 6
// 4738.164 us; speedup vs baseline: 1.2043x; 1.2043x over previous
//
#include <hip/hip_runtime.h>
#include <math.h>

#define TT 9
#define GRU_ROWS 8

typedef __attribute__((ext_vector_type(8))) short bf16x8;
typedef __attribute__((ext_vector_type(4))) float f32x4;

__device__ __forceinline__ unsigned short f2bf(float x) {
    unsigned int u = __float_as_uint(x);
    unsigned int r = (u + 0x7fffu + ((u >> 16) & 1u)) >> 16;
    return (unsigned short)r;
}
__device__ __forceinline__ float bf2f(unsigned short h) {
    return __uint_as_float((unsigned int)h << 16);
}

// ============================================================================
// cvtA: A fp32 [rows,K] -> Ah,Al bf16 [rows,Kp], grid-stride (2048 blocks).
// Only used for the layer-1 peptide input now.
// ============================================================================
__global__ __launch_bounds__(256) void cvta_kernel(
    const float* __restrict__ A, unsigned short* __restrict__ Ah,
    unsigned short* __restrict__ Al, int K, int Kp, unsigned total)
{
    for (unsigned idx = blockIdx.x * 256u + threadIdx.x; idx < total;
         idx += gridDim.x * 256u) {
        unsigned row = idx / (unsigned)Kp;
        unsigned k = idx - row * (unsigned)Kp;
        float v = (k < (unsigned)K) ? A[(size_t)row * K + k] : 0.f;
        unsigned short h = f2bf(v);
        unsigned short l = f2bf(v - bf2f(h));
        Ah[idx] = h;
        Al[idx] = l;
    }
}

// ============================================================================
// cvtW: W fp32 [K,768] -> Wth,Wtl bf16 [768,Kp] TRANSPOSED (zero-padded)
// ============================================================================
__global__ __launch_bounds__(256) void cvtw_kernel(
    const float* __restrict__ W, unsigned short* __restrict__ Wth,
    unsigned short* __restrict__ Wtl, int K, int Kp)
{
    const int n = blockIdx.x * 256 + threadIdx.x;
    const int k = blockIdx.y;
    if (n >= 768) return;
    float v = (k < K) ? W[(size_t)k * 768 + n] : 0.f;
    unsigned short h = f2bf(v);
    unsigned short l = f2bf(v - bf2f(h));
    Wth[(size_t)n * Kp + k] = h;
    Wtl[(size_t)n * Kp + k] = l;
}

// ============================================================================
// projm: C[M,768] = A@W + b via split-bf16 MFMA (Ah*Wh + Ah*Wl + Al*Wh).
// Unchanged from round 5.
// ============================================================================
__global__ __launch_bounds__(256) void projm_kernel(
    const unsigned short* __restrict__ Ah, const unsigned short* __restrict__ Al,
    const unsigned short* __restrict__ Wh, const unsigned short* __restrict__ Wl,
    const float* __restrict__ bs, float* __restrict__ C, int Kp)
{
    __shared__ unsigned short Ah_s[128][40];
    __shared__ unsigned short Al_s[128][40];
    __shared__ unsigned short Wh_s[128][40];
    __shared__ unsigned short Wl_s[128][40];

    const int tid = threadIdx.x;
    const int m0 = blockIdx.y * 128;
    const int n0 = blockIdx.x * 128;

    const int srow = tid >> 1;
    const int skh  = (tid & 1) * 16;

    const unsigned short* pAh = Ah + (size_t)(m0 + srow) * Kp + skh;
    const unsigned short* pAl = Al + (size_t)(m0 + srow) * Kp + skh;
    const unsigned short* pWh = Wh + (size_t)(n0 + srow) * Kp + skh;
    const unsigned short* pWl = Wl + (size_t)(n0 + srow) * Kp + skh;

    const int w    = tid >> 6;
    const int wr   = (w >> 1) * 64;
    const int wc   = (w & 1) * 64;
    const int lane = tid & 63;
    const int lrow = lane & 15;
    const int kg8  = (lane >> 4) * 8;

    f32x4 acc[4][4];
    #pragma unroll
    for (int m = 0; m < 4; ++m)
        #pragma unroll
        for (int n = 0; n < 4; ++n)
            acc[m][n] = (f32x4){0.f, 0.f, 0.f, 0.f};

    uint4 rAh0 = *(const uint4*)(pAh), rAh1 = *(const uint4*)(pAh + 8);
    uint4 rAl0 = *(const uint4*)(pAl), rAl1 = *(const uint4*)(pAl + 8);
    uint4 rWh0 = *(const uint4*)(pWh), rWh1 = *(const uint4*)(pWh + 8);
    uint4 rWl0 = *(const uint4*)(pWl), rWl1 = *(const uint4*)(pWl + 8);
    pAh += 32; pAl += 32; pWh += 32; pWl += 32;

    const int nsteps = Kp >> 5;
    for (int s = 0; s < nsteps; ++s) {
        __syncthreads();
        *(uint4*)&Ah_s[srow][skh]     = rAh0;
        *(uint4*)&Ah_s[srow][skh + 8] = rAh1;
        *(uint4*)&Al_s[srow][skh]     = rAl0;
        *(uint4*)&Al_s[srow][skh + 8] = rAl1;
        *(uint4*)&Wh_s[srow][skh]     = rWh0;
        *(uint4*)&Wh_s[srow][skh + 8] = rWh1;
        *(uint4*)&Wl_s[srow][skh]     = rWl0;
        *(uint4*)&Wl_s[srow][skh + 8] = rWl1;
        __syncthreads();

        if (s + 1 < nsteps) {
            rAh0 = *(const uint4*)(pAh); rAh1 = *(const uint4*)(pAh + 8);
            rAl0 = *(const uint4*)(pAl); rAl1 = *(const uint4*)(pAl + 8);
            rWh0 = *(const uint4*)(pWh); rWh1 = *(const uint4*)(pWh + 8);
            rWl0 = *(const uint4*)(pWl); rWl1 = *(const uint4*)(pWl + 8);
            pAh += 32; pAl += 32; pWh += 32; pWl += 32;
        }

        bf16x8 fa_h[4], fa_l[4], fb_h[4], fb_l[4];
        #pragma unroll
        for (int m = 0; m < 4; ++m) {
            fa_h[m] = *(const bf16x8*)&Ah_s[wr + m * 16 + lrow][kg8];
            fa_l[m] = *(const bf16x8*)&Al_s[wr + m * 16 + lrow][kg8];
        }
        #pragma unroll
        for (int n = 0; n < 4; ++n) {
            fb_h[n] = *(const bf16x8*)&Wh_s[wc + n * 16 + lrow][kg8];
            fb_l[n] = *(const bf16x8*)&Wl_s[wc + n * 16 + lrow][kg8];
        }
        #pragma unroll
        for (int m = 0; m < 4; ++m)
            #pragma unroll
            for (int n = 0; n < 4; ++n) {
                acc[m][n] = __builtin_amdgcn_mfma_f32_16x16x32_bf16(fa_h[m], fb_h[n], acc[m][n], 0, 0, 0);
                acc[m][n] = __builtin_amdgcn_mfma_f32_16x16x32_bf16(fa_h[m], fb_l[n], acc[m][n], 0, 0, 0);
                acc[m][n] = __builtin_amdgcn_mfma_f32_16x16x32_bf16(fa_l[m], fb_h[n], acc[m][n], 0, 0, 0);
            }
    }

    const int orow = (lane >> 4) * 4;
    const int ocol = lane & 15;
    #pragma unroll
    for (int n = 0; n < 4; ++n) {
        const int col = n0 + wc + n * 16 + ocol;
        const float bn = bs[col];
        #pragma unroll
        for (int m = 0; m < 4; ++m) {
            const int rbase = m0 + wr + m * 16 + orow;
            #pragma unroll
            for (int r = 0; r < 4; ++r)
                C[(size_t)(rbase + r) * 768 + col] = acc[m][n][r] + bn;
        }
    }
}

// ============================================================================
// GRU: persistent-h, ONE direction per launch. GRU_ROWS=8 rows/block ->
// grid CB/8 = 2 blocks/CU (was 1) for latency hiding. Thread tid owns gate
// unit tid. Emits y fp32 AND hi/lo bf16 (feeds next layer's projm directly,
// killing the standalone cvta pass).
// ============================================================================
__global__ __launch_bounds__(256) void gru_kernel(
    const float* __restrict__ xp, const float* __restrict__ U, const float* __restrict__ b,
    const float* __restrict__ h0, float* __restrict__ y,
    unsigned short* __restrict__ yh, unsigned short* __restrict__ yl,
    int out_off, int dir)
{
    const float* bi = b + 768;

    __shared__ float h[GRU_ROWS][256];
    const int tid = threadIdx.x;
    const int r0 = blockIdx.x * GRU_ROWS;

    #pragma unroll
    for (int i = 0; i < GRU_ROWS; ++i)
        h[i][tid] = h0 ? h0[(size_t)(r0 + i) * 256 + tid] : 0.f;

    const float bz = bi[tid], br = bi[tid + 256], bh = bi[tid + 512];
    __syncthreads();

    for (int t = 0; t < TT; ++t) {
        const int te = dir ? (TT - 1 - t) : t;
        float acc0[GRU_ROWS], acc1[GRU_ROWS], acc2[GRU_ROWS];
        #pragma unroll
        for (int i = 0; i < GRU_ROWS; ++i) { acc0[i] = 0.f; acc1[i] = 0.f; acc2[i] = 0.f; }

        for (int k = 0; k < 256; k += 8) {
            float w[8][3];
            #pragma unroll
            for (int kk = 0; kk < 8; ++kk) {
                const float* Ur = U + (size_t)(k + kk) * 768;
                w[kk][0] = Ur[tid];
                w[kk][1] = Ur[tid + 256];
                w[kk][2] = Ur[tid + 512];
            }
            #pragma unroll
            for (int i = 0; i < GRU_ROWS; ++i) {
                float4 hv0 = *(const float4*)&h[i][k];
                float4 hv1 = *(const float4*)&h[i][k + 4];
                float hvv[8] = {hv0.x, hv0.y, hv0.z, hv0.w, hv1.x, hv1.y, hv1.z, hv1.w};
                float s0 = acc0[i], s1 = acc1[i], s2 = acc2[i];
                #pragma unroll
                for (int kk = 0; kk < 8; ++kk) {
                    s0 = fmaf(hvv[kk], w[kk][0], s0);
                    s1 = fmaf(hvv[kk], w[kk][1], s1);
                    s2 = fmaf(hvv[kk], w[kk][2], s2);
                }
                acc0[i] = s0; acc1[i] = s1; acc2[i] = s2;
            }
        }
        __syncthreads();
        #pragma unroll
        for (int i = 0; i < GRU_ROWS; ++i) {
            const size_t xb = ((size_t)(r0 + i) * TT + te) * 768;
            float xz = xp[xb + tid];
            float xr = xp[xb + tid + 256];
            float xh = xp[xb + tid + 512];
            float z  = 1.f / (1.f + expf(-(xz + acc0[i] + bz)));
            float r  = 1.f / (1.f + expf(-(xr + acc1[i] + br)));
            float hh = tanhf(xh + r * (acc2[i] + bh));
            float hold = h[i][tid];
            float hn = z * hold + (1.f - z) * hh;
            h[i][tid] = hn;
            const size_t yi = ((size_t)(r0 + i) * TT + te) * 512 + out_off + tid;
            y[yi] = hn;
            unsigned short hb = f2bf(hn);
            yh[yi] = hb;
            yl[yi] = f2bf(hn - bf2f(hb));
        }
        __syncthreads();
    }
}

// ============================================================================
// score / softmax+ctx / fc (unchanged)
// ============================================================================
__global__ __launch_bounds__(256) void score_kernel(
    const float* __restrict__ Y, const float* __restrict__ W1, const float* __restrict__ b1,
    const float* __restrict__ V, const float* __restrict__ bV,
    float* __restrict__ score)
{
    __shared__ float ylds[16][512];
    __shared__ float sred[16][256];
    const int tid = threadIdx.x;
    const int r0 = blockIdx.x * 16;

    for (int idx = tid; idx < 16 * 512; idx += 256)
        ylds[idx >> 9][idx & 511] = Y[(size_t)r0 * 512 + idx];
    __syncthreads();

    float acc0[16], acc1[16];
    #pragma unroll
    for (int i = 0; i < 16; ++i) { acc0[i] = 0.f; acc1[i] = 0.f; }

    for (int k = 0; k < 512; k += 8) {
        float w[8][2];
        #pragma unroll
        for (int kk = 0; kk < 8; ++kk) {
            const float* Wr = W1 + (size_t)(k + kk) * 512;
            w[kk][0] = Wr[tid];
            w[kk][1] = Wr[tid + 256];
        }
        #pragma unroll
        for (int i = 0; i < 16; ++i) {
            float4 y0 = *(const float4*)&ylds[i][k];
            float4 y1 = *(const float4*)&ylds[i][k + 4];
            float yv[8] = {y0.x, y0.y, y0.z, y0.w, y1.x, y1.y, y1.z, y1.w};
            float s0 = acc0[i], s1 = acc1[i];
            #pragma unroll
            for (int kk = 0; kk < 8; ++kk) {
                s0 = fmaf(yv[kk], w[kk][0], s0);
                s1 = fmaf(yv[kk], w[kk][1], s1);
            }
            acc0[i] = s0; acc1[i] = s1;
        }
    }
    const float v0 = V[tid], v1 = V[tid + 256];
    const float c0 = b1[tid], c1 = b1[tid + 256];
    #pragma unroll
    for (int i = 0; i < 16; ++i)
        sred[i][tid] = tanhf(acc0[i] + c0) * v0 + tanhf(acc1[i] + c1) * v1;
    __syncthreads();
    const int wave = tid >> 6, lane = tid & 63;
    for (int i = wave * 4; i < wave * 4 + 4; ++i) {
        float s = sred[i][lane] + sred[i][lane + 64] + sred[i][lane + 128] + sred[i][lane + 192];
        #pragma unroll
        for (int off = 32; off > 0; off >>= 1) s += __shfl_down(s, off);
        if (lane == 0) score[r0 + i] = s + bV[0];
    }
}

__global__ __launch_bounds__(64) void softmax_ctx_kernel(
    const float* __restrict__ score, const float* __restrict__ Y,
    float* __restrict__ ctx, float* __restrict__ att)
{
    const int b = blockIdx.x;
    const int lane = threadIdx.x;
    __shared__ float wv[TT];
    float s = (lane < TT) ? score[(size_t)b * TT + lane] : -3.0e38f;
    float m = s;
    #pragma unroll
    for (int off = 32; off > 0; off >>= 1) m = fmaxf(m, __shfl_xor(m, off));
    float e = (lane < TT) ? expf(s - m) : 0.f;
    float sum = e;
    #pragma unroll
    for (int off = 32; off > 0; off >>= 1) sum += __shfl_xor(sum, off);
    float wgt = e / sum;
    if (lane < TT) { att[(size_t)b * TT + lane] = wgt; wv[lane] = wgt; }
    __syncthreads();
    float wr[TT];
    #pragma unroll
    for (int t2 = 0; t2 < TT; ++t2) wr[t2] = wv[t2];
    #pragma unroll
    for (int j = 0; j < 8; ++j) {
        int c = lane + j * 64;
        float a = 0.f;
        #pragma unroll
        for (int t2 = 0; t2 < TT; ++t2)
            a = fmaf(wr[t2], Y[((size_t)b * TT + t2) * 512 + c], a);
        ctx[(size_t)b * 512 + c] = a;
    }
}

__global__ __launch_bounds__(256) void fc_kernel(
    const float* __restrict__ ctx, const float* __restrict__ W1, const float* __restrict__ b1,
    const float* __restrict__ W2, const float* __restrict__ b2,
    float* __restrict__ logits)
{
    __shared__ float clds[16][512];
    const int tid = threadIdx.x;
    const int r0 = blockIdx.x * 16;
    for (int idx = tid; idx < 16 * 512; idx += 256)
        clds[idx >> 9][idx & 511] = ctx[(size_t)r0 * 512 + idx];
    __syncthreads();

    float acc0[16], acc1[16];
    #pragma unroll
    for (int i = 0; i < 16; ++i) { acc0[i] = 0.f; acc1[i] = 0.f; }

    for (int k = 0; k < 512; k += 8) {
        float w[8][2];
        #pragma unroll
        for (int kk = 0; kk < 8; ++kk) {
            const float* Wr = W1 + (size_t)(k + kk) * 512;
            w[kk][0] = Wr[tid];
            w[kk][1] = Wr[tid + 256];
        }
        #pragma unroll
        for (int i = 0; i < 16; ++i) {
            float4 y0 = *(const float4*)&clds[i][k];
            float4 y1 = *(const float4*)&clds[i][k + 4];
            float yv[8] = {y0.x, y0.y, y0.z, y0.w, y1.x, y1.y, y1.z, y1.w};
            float s0 = acc0[i], s1 = acc1[i];
            #pragma unroll
            for (int kk = 0; kk < 8; ++kk) {
                s0 = fmaf(yv[kk], w[kk][0], s0);
                s1 = fmaf(yv[kk], w[kk][1], s1);
            }
            acc0[i] = s0; acc1[i] = s1;
        }
    }
    const float w2a0 = W2[(size_t)tid * 2],         w2a1 = W2[(size_t)tid * 2 + 1];
    const float w2b0 = W2[(size_t)(tid + 256) * 2], w2b1 = W2[(size_t)(tid + 256) * 2 + 1];
    const float c0 = b1[tid], c1 = b1[tid + 256];
    __syncthreads();
    #pragma unroll
    for (int i = 0; i < 16; ++i) {
        float h0 = fmaxf(acc0[i] + c0, 0.f);
        float h1 = fmaxf(acc1[i] + c1, 0.f);
        clds[i][tid * 2]     = fmaf(h0, w2a0, h1 * w2b0);
        clds[i][tid * 2 + 1] = fmaf(h0, w2a1, h1 * w2b1);
    }
    __syncthreads();
    const int wave = tid >> 6, lane = tid & 63;
    for (int i = wave * 4; i < wave * 4 + 4; ++i) {
        float px = clds[i][lane * 2]     + clds[i][(lane + 64) * 2]     + clds[i][(lane + 128) * 2]     + clds[i][(lane + 192) * 2];
        float py = clds[i][lane * 2 + 1] + clds[i][(lane + 64) * 2 + 1] + clds[i][(lane + 128) * 2 + 1] + clds[i][(lane + 192) * 2 + 1];
        #pragma unroll
        for (int off = 32; off > 0; off >>= 1) { px += __shfl_down(px, off); py += __shfl_down(py, off); }
        if (lane == 0) {
            logits[(size_t)(r0 + i) * 2]     = px + b2[0];
            logits[(size_t)(r0 + i) * 2 + 1] = py + b2[1];
        }
    }
}

// ============================================================================
extern "C" void kernel_launch(void* const* d_in, const int* in_sizes, int n_in,
                              void* d_out, int out_size, void* d_ws, size_t ws_size,
                              hipStream_t stream)
{
    const float* peptide = (const float*)d_in[0];
    const float* hidden  = (const float*)d_in[1];
    const float* gW[6] = { (const float*)d_in[2],  (const float*)d_in[5],
                           (const float*)d_in[8],  (const float*)d_in[11],
                           (const float*)d_in[14], (const float*)d_in[17] };
    const float* gU[6] = { (const float*)d_in[3],  (const float*)d_in[6],
                           (const float*)d_in[9],  (const float*)d_in[12],
                           (const float*)d_in[15], (const float*)d_in[18] };
    const float* gB[6] = { (const float*)d_in[4],  (const float*)d_in[7],
                           (const float*)d_in[10], (const float*)d_in[13],
                           (const float*)d_in[16], (const float*)d_in[19] };
    const float* att_W1 = (const float*)d_in[20];
    const float* att_b1 = (const float*)d_in[21];
    const float* att_V  = (const float*)d_in[22];
    const float* att_bV = (const float*)d_in[23];
    const float* fc1_W = (const float*)d_in[24];
    const float* fc1_b = (const float*)d_in[25];
    const float* fc2_W = (const float*)d_in[26];
    const float* fc2_b = (const float*)d_in[27];

    float* out = (float*)d_out;   // [0,8192) logits, [8192,45056) attention weights

    // Workspace budget per chunk (bytes):
    //   xp  [CB*9,768] f32            (proj output / score+ctx scratch)
    //   yAf [CB*9,512] f32            (fp32 y, only layer 3's survives)
    //   R2  (yAh,yAl) [CB*9,512] bf16 (layer-1 y bf16)
    //   R1  (Aph,Apl) [CB*9,576] bf16 (peptide bf16; reused as layer-2 y bf16)
    //   Wt  (Wth,Wtl) [768,576] bf16
    int NC = 1;
    size_t CB = 4096;
    for (; NC <= 32; NC *= 2) {
        CB = 4096 / NC;
        size_t bytes = (size_t)CB * TT * 768 * 4 + (size_t)CB * TT * 512 * 4
                     + 2 * (size_t)CB * TT * 512 * 2 + 2 * (size_t)CB * TT * 576 * 2
                     + 2 * (size_t)768 * 576 * 2;
        if (bytes <= ws_size) break;
    }
    if (NC > 32) { NC = 32; CB = 128; }

    char* ws = (char*)d_ws;
    float* xp  = (float*)ws;                                  ws += (size_t)CB * TT * 768 * 4;
    float* yAf = (float*)ws;                                  ws += (size_t)CB * TT * 512 * 4;
    unsigned short* yAh = (unsigned short*)ws;                ws += (size_t)CB * TT * 512 * 2;
    unsigned short* yAl = (unsigned short*)ws;                ws += (size_t)CB * TT * 512 * 2;
    unsigned short* Aph = (unsigned short*)ws;                ws += (size_t)CB * TT * 576 * 2;
    unsigned short* Apl = (unsigned short*)ws;                ws += (size_t)CB * TT * 576 * 2;
    unsigned short* Wth = (unsigned short*)ws;                ws += (size_t)768 * 576 * 2;
    unsigned short* Wtl = (unsigned short*)ws;
    // layer-2 y bf16 aliases the (dead) peptide bf16 region:
    unsigned short* yBh = Aph;
    unsigned short* yBl = Apl;
    // score/ctx reuse the xp region (dead after the last gru):
    float* score = xp;
    float* ctx   = xp + (((size_t)CB * TT + 255) & ~(size_t)255);

    const int M = (int)CB * TT;                      // rows per chunk
    dim3 pb(256), pg(6, M / 128);                    // projm: N/128 x M/128
    dim3 gb(256), gg((unsigned)CB / GRU_ROWS);       // gru: CB/8 blocks
    dim3 cab(256);

    for (int c = 0; c < NC; ++c) {
        const float* pep_c = peptide + (size_t)c * CB * TT * 553;
        const float* hid_c = hidden + (size_t)c * CB * 256;
        float* logits_c = out + (size_t)c * CB * 2;
        float* att_c    = out + 8192 + (size_t)c * CB * TT;

        // ---- layer 1 (K=553 -> Kp=576, h0 = hidden, both dirs share A) ----
        cvta_kernel<<<dim3(2048), cab, 0, stream>>>(pep_c, Aph, Apl, 553, 576, (unsigned)M * 576u);
        cvtw_kernel<<<dim3(3, 576), cab, 0, stream>>>(gW[0], Wth, Wtl, 553, 576);
        projm_kernel<<<pg, pb, 0, stream>>>(Aph, Apl, Wth, Wtl, gB[0], xp, 576);
        gru_kernel<<<gg, gb, 0, stream>>>(xp, gU[0], gB[0], hid_c, yAf, yAh, yAl, 0, 0);
        cvtw_kernel<<<dim3(3, 576), cab, 0, stream>>>(gW[1], Wth, Wtl, 553, 576);
        projm_kernel<<<pg, pb, 0, stream>>>(Aph, Apl, Wth, Wtl, gB[1], xp, 576);
        gru_kernel<<<gg, gb, 0, stream>>>(xp, gU[1], gB[1], hid_c, yAf, yAh, yAl, 256, 1);
        // peptide bf16 (Aph/Apl) dead from here; region reused as yBh/yBl.

        // ---- layer 2 (K=512, h0 = 0); A = layer-1 y bf16 ----
        cvtw_kernel<<<dim3(3, 512), cab, 0, stream>>>(gW[2], Wth, Wtl, 512, 512);
        projm_kernel<<<pg, pb, 0, stream>>>(yAh, yAl, Wth, Wtl, gB[2], xp, 512);
        gru_kernel<<<gg, gb, 0, stream>>>(xp, gU[2], gB[2], nullptr, yAf, yBh, yBl, 0, 0);
        cvtw_kernel<<<dim3(3, 512), cab, 0, stream>>>(gW[3], Wth, Wtl, 512, 512);
        projm_kernel<<<pg, pb, 0, stream>>>(yAh, yAl, Wth, Wtl, gB[3], xp, 512);
        gru_kernel<<<gg, gb, 0, stream>>>(xp, gU[3], gB[3], nullptr, yAf, yBh, yBl, 256, 1);

        // ---- layer 3; A = layer-2 y bf16; fp32 y survives for attention ----
        cvtw_kernel<<<dim3(3, 512), cab, 0, stream>>>(gW[4], Wth, Wtl, 512, 512);
        projm_kernel<<<pg, pb, 0, stream>>>(yBh, yBl, Wth, Wtl, gB[4], xp, 512);
        gru_kernel<<<gg, gb, 0, stream>>>(xp, gU[4], gB[4], nullptr, yAf, yAh, yAl, 0, 0);
        cvtw_kernel<<<dim3(3, 512), cab, 0, stream>>>(gW[5], Wth, Wtl, 512, 512);
        projm_kernel<<<pg, pb, 0, stream>>>(yBh, yBl, Wth, Wtl, gB[5], xp, 512);
        gru_kernel<<<gg, gb, 0, stream>>>(xp, gU[5], gB[5], nullptr, yAf, yAh, yAl, 256, 1);

        // ---- attention + head ----
        score_kernel<<<dim3(M / 16), dim3(256), 0, stream>>>(yAf, att_W1, att_b1, att_V, att_bV, score);
        softmax_ctx_kernel<<<dim3((unsigned)CB), dim3(64), 0, stream>>>(score, yAf, ctx, att_c);
        fc_kernel<<<dim3((unsigned)CB / 16), dim3(256), 0, stream>>>(ctx, fc1_W, fc1_b, fc2_W, fc2_b, logits_c);
    }
}

// Round 7
// 3686.974 us; speedup vs baseline: 1.5476x; 1.2851x over previous
//
#include <hip/hip_runtime.h>
#include <math.h>

#define TT 9
#define GRU_ROWS 8

typedef __attribute__((ext_vector_type(8))) short bf16x8;
typedef __attribute__((ext_vector_type(4))) float f32x4;

__device__ __forceinline__ unsigned short f2bf(float x) {
    unsigned int u = __float_as_uint(x);
    unsigned int r = (u + 0x7fffu + ((u >> 16) & 1u)) >> 16;
    return (unsigned short)r;
}
__device__ __forceinline__ float bf2f(unsigned short h) {
    return __uint_as_float((unsigned int)h << 16);
}

// ============================================================================
// cvtA: A fp32 [rows,K] -> Ah,Al bf16 [rows,Kp], grid-stride. (peptide only)
// ============================================================================
__global__ __launch_bounds__(256) void cvta_kernel(
    const float* __restrict__ A, unsigned short* __restrict__ Ah,
    unsigned short* __restrict__ Al, int K, int Kp, unsigned total)
{
    for (unsigned idx = blockIdx.x * 256u + threadIdx.x; idx < total;
         idx += gridDim.x * 256u) {
        unsigned row = idx / (unsigned)Kp;
        unsigned k = idx - row * (unsigned)Kp;
        float v = (k < (unsigned)K) ? A[(size_t)row * K + k] : 0.f;
        unsigned short h = f2bf(v);
        unsigned short l = f2bf(v - bf2f(h));
        Ah[idx] = h;
        Al[idx] = l;
    }
}

// ============================================================================
// cvtW: W fp32 [K,N] -> Wth,Wtl bf16 [N,Kp] TRANSPOSED (zero-padded). N<=768.
// ============================================================================
__global__ __launch_bounds__(256) void cvtw_kernel(
    const float* __restrict__ W, unsigned short* __restrict__ Wth,
    unsigned short* __restrict__ Wtl, int K, int Kp, int N)
{
    const int n = blockIdx.x * 256 + threadIdx.x;
    const int k = blockIdx.y;
    if (n >= N) return;
    float v = (k < K) ? W[(size_t)k * N + n] : 0.f;
    unsigned short h = f2bf(v);
    unsigned short l = f2bf(v - bf2f(h));
    Wth[(size_t)n * Kp + k] = h;
    Wtl[(size_t)n * Kp + k] = l;
}

// ============================================================================
// cvtU: U fp32 [256,768] -> Up float2-packed: Up[(k2*3+j)*256+u] =
// {U[2k2][j*256+u], U[2k2+1][j*256+u]}. Exact fp32 copy (no precision loss).
// total pairs = 128*768 = 98304 -> grid 384.
// ============================================================================
__global__ __launch_bounds__(256) void cvtu_kernel(
    const float* __restrict__ U, float2* __restrict__ Up)
{
    unsigned p = blockIdx.x * 256u + threadIdx.x;
    if (p >= 98304u) return;
    unsigned k2 = p / 768u;
    unsigned r  = p - k2 * 768u;
    float a = U[(size_t)(2 * k2) * 768 + r];
    float b = U[(size_t)(2 * k2 + 1) * 768 + r];
    Up[p] = make_float2(a, b);
}

// ============================================================================
// projm: C[M,N] = A@W + b via split-bf16 MFMA (Ah*Wh + Ah*Wl + Al*Wh).
// N parameterized (512 for attention GEMM, 768 for GRU projections).
// ============================================================================
__global__ __launch_bounds__(256) void projm_kernel(
    const unsigned short* __restrict__ Ah, const unsigned short* __restrict__ Al,
    const unsigned short* __restrict__ Wh, const unsigned short* __restrict__ Wl,
    const float* __restrict__ bs, float* __restrict__ C, int Kp, int N)
{
    __shared__ unsigned short Ah_s[128][40];
    __shared__ unsigned short Al_s[128][40];
    __shared__ unsigned short Wh_s[128][40];
    __shared__ unsigned short Wl_s[128][40];

    const int tid = threadIdx.x;
    const int m0 = blockIdx.y * 128;
    const int n0 = blockIdx.x * 128;

    const int srow = tid >> 1;
    const int skh  = (tid & 1) * 16;

    const unsigned short* pAh = Ah + (size_t)(m0 + srow) * Kp + skh;
    const unsigned short* pAl = Al + (size_t)(m0 + srow) * Kp + skh;
    const unsigned short* pWh = Wh + (size_t)(n0 + srow) * Kp + skh;
    const unsigned short* pWl = Wl + (size_t)(n0 + srow) * Kp + skh;

    const int w    = tid >> 6;
    const int wr   = (w >> 1) * 64;
    const int wc   = (w & 1) * 64;
    const int lane = tid & 63;
    const int lrow = lane & 15;
    const int kg8  = (lane >> 4) * 8;

    f32x4 acc[4][4];
    #pragma unroll
    for (int m = 0; m < 4; ++m)
        #pragma unroll
        for (int n = 0; n < 4; ++n)
            acc[m][n] = (f32x4){0.f, 0.f, 0.f, 0.f};

    uint4 rAh0 = *(const uint4*)(pAh), rAh1 = *(const uint4*)(pAh + 8);
    uint4 rAl0 = *(const uint4*)(pAl), rAl1 = *(const uint4*)(pAl + 8);
    uint4 rWh0 = *(const uint4*)(pWh), rWh1 = *(const uint4*)(pWh + 8);
    uint4 rWl0 = *(const uint4*)(pWl), rWl1 = *(const uint4*)(pWl + 8);
    pAh += 32; pAl += 32; pWh += 32; pWl += 32;

    const int nsteps = Kp >> 5;
    for (int s = 0; s < nsteps; ++s) {
        __syncthreads();
        *(uint4*)&Ah_s[srow][skh]     = rAh0;
        *(uint4*)&Ah_s[srow][skh + 8] = rAh1;
        *(uint4*)&Al_s[srow][skh]     = rAl0;
        *(uint4*)&Al_s[srow][skh + 8] = rAl1;
        *(uint4*)&Wh_s[srow][skh]     = rWh0;
        *(uint4*)&Wh_s[srow][skh + 8] = rWh1;
        *(uint4*)&Wl_s[srow][skh]     = rWl0;
        *(uint4*)&Wl_s[srow][skh + 8] = rWl1;
        __syncthreads();

        if (s + 1 < nsteps) {
            rAh0 = *(const uint4*)(pAh); rAh1 = *(const uint4*)(pAh + 8);
            rAl0 = *(const uint4*)(pAl); rAl1 = *(const uint4*)(pAl + 8);
            rWh0 = *(const uint4*)(pWh); rWh1 = *(const uint4*)(pWh + 8);
            rWl0 = *(const uint4*)(pWl); rWl1 = *(const uint4*)(pWl + 8);
            pAh += 32; pAl += 32; pWh += 32; pWl += 32;
        }

        bf16x8 fa_h[4], fa_l[4], fb_h[4], fb_l[4];
        #pragma unroll
        for (int m = 0; m < 4; ++m) {
            fa_h[m] = *(const bf16x8*)&Ah_s[wr + m * 16 + lrow][kg8];
            fa_l[m] = *(const bf16x8*)&Al_s[wr + m * 16 + lrow][kg8];
        }
        #pragma unroll
        for (int n = 0; n < 4; ++n) {
            fb_h[n] = *(const bf16x8*)&Wh_s[wc + n * 16 + lrow][kg8];
            fb_l[n] = *(const bf16x8*)&Wl_s[wc + n * 16 + lrow][kg8];
        }
        #pragma unroll
        for (int m = 0; m < 4; ++m)
            #pragma unroll
            for (int n = 0; n < 4; ++n) {
                acc[m][n] = __builtin_amdgcn_mfma_f32_16x16x32_bf16(fa_h[m], fb_h[n], acc[m][n], 0, 0, 0);
                acc[m][n] = __builtin_amdgcn_mfma_f32_16x16x32_bf16(fa_h[m], fb_l[n], acc[m][n], 0, 0, 0);
                acc[m][n] = __builtin_amdgcn_mfma_f32_16x16x32_bf16(fa_l[m], fb_h[n], acc[m][n], 0, 0, 0);
            }
    }

    const int orow = (lane >> 4) * 4;
    const int ocol = lane & 15;
    #pragma unroll
    for (int n = 0; n < 4; ++n) {
        const int col = n0 + wc + n * 16 + ocol;
        const float bn = bs[col];
        #pragma unroll
        for (int m = 0; m < 4; ++m) {
            const int rbase = m0 + wr + m * 16 + orow;
            #pragma unroll
            for (int r = 0; r < 4; ++r)
                C[(size_t)(rbase + r) * N + col] = acc[m][n][r] + bn;
        }
    }
}

// ============================================================================
// GRU helpers: chunk c covers k = 8c..8c+7 (4 packed float2 pairs x 3 gates).
// ============================================================================
__device__ __forceinline__ void gru_loadw(const float2* __restrict__ Up, int c,
                                          int tid, float2 (&w)[12])
{
    const float2* q = Up + (size_t)c * 12 * 256 + tid;
    #pragma unroll
    for (int i = 0; i < 12; ++i) w[i] = q[(size_t)i * 256];
}

__device__ __forceinline__ void gru_chunk(const float (*h)[256], int c,
    const float2 (&w)[12], float (&a0)[GRU_ROWS], float (&a1)[GRU_ROWS],
    float (&a2)[GRU_ROWS])
{
    #pragma unroll
    for (int i = 0; i < GRU_ROWS; ++i) {
        float4 hv0 = *(const float4*)&h[i][c * 8];
        float4 hv1 = *(const float4*)&h[i][c * 8 + 4];
        float hv[8] = {hv0.x, hv0.y, hv0.z, hv0.w, hv1.x, hv1.y, hv1.z, hv1.w};
        float s0 = a0[i], s1 = a1[i], s2 = a2[i];
        #pragma unroll
        for (int kk = 0; kk < 8; ++kk) {
            const int q = kk >> 1;
            const float wz = (kk & 1) ? w[q * 3 + 0].y : w[q * 3 + 0].x;
            const float wr = (kk & 1) ? w[q * 3 + 1].y : w[q * 3 + 1].x;
            const float wh = (kk & 1) ? w[q * 3 + 2].y : w[q * 3 + 2].x;
            s0 = fmaf(hv[kk], wz, s0);
            s1 = fmaf(hv[kk], wr, s1);
            s2 = fmaf(hv[kk], wh, s2);
        }
        a0[i] = s0; a1[i] = s1; a2[i] = s2;
    }
}

// ============================================================================
// GRU: persistent-h, ONE direction per launch, 8 rows/block (2 blocks/CU).
// U pre-packed as float2 pairs; double-buffered register prefetch hides L2
// latency under the FMA stream. Emits y fp32 AND hi/lo bf16.
// ============================================================================
__global__ __launch_bounds__(256) void gru_kernel(
    const float* __restrict__ xp, const float2* __restrict__ Up,
    const float* __restrict__ b, const float* __restrict__ h0,
    float* __restrict__ y, unsigned short* __restrict__ yh,
    unsigned short* __restrict__ yl, int out_off, int dir)
{
    const float* bi = b + 768;

    __shared__ float h[GRU_ROWS][256];
    const int tid = threadIdx.x;
    const int r0 = blockIdx.x * GRU_ROWS;

    #pragma unroll
    for (int i = 0; i < GRU_ROWS; ++i)
        h[i][tid] = h0 ? h0[(size_t)(r0 + i) * 256 + tid] : 0.f;

    const float bz = bi[tid], br = bi[tid + 256], bh = bi[tid + 512];
    __syncthreads();

    for (int t = 0; t < TT; ++t) {
        const int te = dir ? (TT - 1 - t) : t;
        float acc0[GRU_ROWS], acc1[GRU_ROWS], acc2[GRU_ROWS];
        #pragma unroll
        for (int i = 0; i < GRU_ROWS; ++i) { acc0[i] = 0.f; acc1[i] = 0.f; acc2[i] = 0.f; }

        float2 wa[12], wb[12];
        gru_loadw(Up, 0, tid, wa);
        for (int c = 0; c < 32; c += 2) {
            gru_loadw(Up, c + 1, tid, wb);            // prefetch odd chunk
            gru_chunk(h, c, wa, acc0, acc1, acc2);    // compute even chunk
            if (c + 2 < 32) gru_loadw(Up, c + 2, tid, wa);  // prefetch next even
            gru_chunk(h, c + 1, wb, acc0, acc1, acc2);      // compute odd
        }
        __syncthreads();
        #pragma unroll
        for (int i = 0; i < GRU_ROWS; ++i) {
            const size_t xb = ((size_t)(r0 + i) * TT + te) * 768;
            float xz = xp[xb + tid];
            float xr = xp[xb + tid + 256];
            float xh = xp[xb + tid + 512];
            float z  = 1.f / (1.f + expf(-(xz + acc0[i] + bz)));
            float r  = 1.f / (1.f + expf(-(xr + acc1[i] + br)));
            float hh = tanhf(xh + r * (acc2[i] + bh));
            float hold = h[i][tid];
            float hn = z * hold + (1.f - z) * hh;
            h[i][tid] = hn;
            const size_t yi = ((size_t)(r0 + i) * TT + te) * 512 + out_off + tid;
            y[yi] = hn;
            unsigned short hb = f2bf(hn);
            yh[yi] = hb;
            yl[yi] = f2bf(hn - bf2f(hb));
        }
        __syncthreads();
    }
}

// ============================================================================
// tail: per batch row b (64 lanes): score_t = tanh-free dot of precomputed
// H=Y@W1+b1 through tanh with V, softmax over T, att write, ctx = sum w_t*Y.
// ============================================================================
__global__ __launch_bounds__(64) void tail_kernel(
    const float* __restrict__ H, const float* __restrict__ Y,
    const float* __restrict__ V, const float* __restrict__ bV,
    float* __restrict__ ctx, float* __restrict__ att)
{
    const int b = blockIdx.x;
    const int lane = threadIdx.x;

    float sc[TT];
    #pragma unroll
    for (int t = 0; t < TT; ++t) {
        const float* Hp = H + ((size_t)b * TT + t) * 512;
        float s = 0.f;
        #pragma unroll
        for (int j = 0; j < 8; ++j) {
            int cix = lane + j * 64;
            s = fmaf(tanhf(Hp[cix]), V[cix], s);
        }
        #pragma unroll
        for (int off = 32; off > 0; off >>= 1) s += __shfl_xor(s, off);
        sc[t] = s + bV[0];
    }
    float m = sc[0];
    #pragma unroll
    for (int t = 1; t < TT; ++t) m = fmaxf(m, sc[t]);
    float sum = 0.f;
    float wt[TT];
    #pragma unroll
    for (int t = 0; t < TT; ++t) { wt[t] = expf(sc[t] - m); sum += wt[t]; }
    const float inv = 1.f / sum;
    #pragma unroll
    for (int t = 0; t < TT; ++t) {
        wt[t] *= inv;
        if (lane == t) att[(size_t)b * TT + t] = wt[t];
    }
    #pragma unroll
    for (int j = 0; j < 8; ++j) {
        int cix = lane + j * 64;
        float a = 0.f;
        #pragma unroll
        for (int t = 0; t < TT; ++t)
            a = fmaf(wt[t], Y[((size_t)b * TT + t) * 512 + cix], a);
        ctx[(size_t)b * 512 + cix] = a;
    }
}

// ============================================================================
// fused FC1(relu) + FC2 -> logits [rows,2] (unchanged)
// ============================================================================
__global__ __launch_bounds__(256) void fc_kernel(
    const float* __restrict__ ctx, const float* __restrict__ W1, const float* __restrict__ b1,
    const float* __restrict__ W2, const float* __restrict__ b2,
    float* __restrict__ logits)
{
    __shared__ float clds[16][512];
    const int tid = threadIdx.x;
    const int r0 = blockIdx.x * 16;
    for (int idx = tid; idx < 16 * 512; idx += 256)
        clds[idx >> 9][idx & 511] = ctx[(size_t)r0 * 512 + idx];
    __syncthreads();

    float acc0[16], acc1[16];
    #pragma unroll
    for (int i = 0; i < 16; ++i) { acc0[i] = 0.f; acc1[i] = 0.f; }

    for (int k = 0; k < 512; k += 8) {
        float w[8][2];
        #pragma unroll
        for (int kk = 0; kk < 8; ++kk) {
            const float* Wr = W1 + (size_t)(k + kk) * 512;
            w[kk][0] = Wr[tid];
            w[kk][1] = Wr[tid + 256];
        }
        #pragma unroll
        for (int i = 0; i < 16; ++i) {
            float4 y0 = *(const float4*)&clds[i][k];
            float4 y1 = *(const float4*)&clds[i][k + 4];
            float yv[8] = {y0.x, y0.y, y0.z, y0.w, y1.x, y1.y, y1.z, y1.w};
            float s0 = acc0[i], s1 = acc1[i];
            #pragma unroll
            for (int kk = 0; kk < 8; ++kk) {
                s0 = fmaf(yv[kk], w[kk][0], s0);
                s1 = fmaf(yv[kk], w[kk][1], s1);
            }
            acc0[i] = s0; acc1[i] = s1;
        }
    }
    const float w2a0 = W2[(size_t)tid * 2],         w2a1 = W2[(size_t)tid * 2 + 1];
    const float w2b0 = W2[(size_t)(tid + 256) * 2], w2b1 = W2[(size_t)(tid + 256) * 2 + 1];
    const float c0 = b1[tid], c1 = b1[tid + 256];
    __syncthreads();
    #pragma unroll
    for (int i = 0; i < 16; ++i) {
        float h0 = fmaxf(acc0[i] + c0, 0.f);
        float h1 = fmaxf(acc1[i] + c1, 0.f);
        clds[i][tid * 2]     = fmaf(h0, w2a0, h1 * w2b0);
        clds[i][tid * 2 + 1] = fmaf(h0, w2a1, h1 * w2b1);
    }
    __syncthreads();
    const int wave = tid >> 6, lane = tid & 63;
    for (int i = wave * 4; i < wave * 4 + 4; ++i) {
        float px = clds[i][lane * 2]     + clds[i][(lane + 64) * 2]     + clds[i][(lane + 128) * 2]     + clds[i][(lane + 192) * 2];
        float py = clds[i][lane * 2 + 1] + clds[i][(lane + 64) * 2 + 1] + clds[i][(lane + 128) * 2 + 1] + clds[i][(lane + 192) * 2 + 1];
        #pragma unroll
        for (int off = 32; off > 0; off >>= 1) { px += __shfl_down(px, off); py += __shfl_down(py, off); }
        if (lane == 0) {
            logits[(size_t)(r0 + i) * 2]     = px + b2[0];
            logits[(size_t)(r0 + i) * 2 + 1] = py + b2[1];
        }
    }
}

// ============================================================================
extern "C" void kernel_launch(void* const* d_in, const int* in_sizes, int n_in,
                              void* d_out, int out_size, void* d_ws, size_t ws_size,
                              hipStream_t stream)
{
    const float* peptide = (const float*)d_in[0];
    const float* hidden  = (const float*)d_in[1];
    const float* gW[6] = { (const float*)d_in[2],  (const float*)d_in[5],
                           (const float*)d_in[8],  (const float*)d_in[11],
                           (const float*)d_in[14], (const float*)d_in[17] };
    const float* gU[6] = { (const float*)d_in[3],  (const float*)d_in[6],
                           (const float*)d_in[9],  (const float*)d_in[12],
                           (const float*)d_in[15], (const float*)d_in[18] };
    const float* gB[6] = { (const float*)d_in[4],  (const float*)d_in[7],
                           (const float*)d_in[10], (const float*)d_in[13],
                           (const float*)d_in[16], (const float*)d_in[19] };
    const float* att_W1 = (const float*)d_in[20];
    const float* att_b1 = (const float*)d_in[21];
    const float* att_V  = (const float*)d_in[22];
    const float* att_bV = (const float*)d_in[23];
    const float* fc1_W = (const float*)d_in[24];
    const float* fc1_b = (const float*)d_in[25];
    const float* fc2_W = (const float*)d_in[26];
    const float* fc2_b = (const float*)d_in[27];

    float* out = (float*)d_out;   // [0,8192) logits, [8192,45056) attention weights

    // Workspace per chunk (bytes):
    //   xp [CB*9,768] f32, yAf [CB*9,512] f32, yAh/yAl [CB*9,512] bf16,
    //   Aph/Apl [CB*9,576] bf16 (reused as layer-2 y bf16),
    //   Wth/Wtl [768,576] bf16, Upf/Upb 786KB each.
    int NC = 1;
    size_t CB = 4096;
    for (; NC <= 32; NC *= 2) {
        CB = 4096 / NC;
        size_t bytes = (size_t)CB * TT * 768 * 4 + (size_t)CB * TT * 512 * 4
                     + 2 * (size_t)CB * TT * 512 * 2 + 2 * (size_t)CB * TT * 576 * 2
                     + 2 * (size_t)768 * 576 * 2 + 2 * (size_t)98304 * 8;
        if (bytes <= ws_size) break;
    }
    if (NC > 32) { NC = 32; CB = 128; }

    char* ws = (char*)d_ws;
    float* xp  = (float*)ws;                                  ws += (size_t)CB * TT * 768 * 4;
    float* yAf = (float*)ws;                                  ws += (size_t)CB * TT * 512 * 4;
    unsigned short* yAh = (unsigned short*)ws;                ws += (size_t)CB * TT * 512 * 2;
    unsigned short* yAl = (unsigned short*)ws;                ws += (size_t)CB * TT * 512 * 2;
    unsigned short* Aph = (unsigned short*)ws;                ws += (size_t)CB * TT * 576 * 2;
    unsigned short* Apl = (unsigned short*)ws;                ws += (size_t)CB * TT * 576 * 2;
    unsigned short* Wth = (unsigned short*)ws;                ws += (size_t)768 * 576 * 2;
    unsigned short* Wtl = (unsigned short*)ws;                ws += (size_t)768 * 576 * 2;
    float2* Upf = (float2*)ws;                                ws += (size_t)98304 * 8;
    float2* Upb = (float2*)ws;
    // aliases:
    unsigned short* yBh = Aph;          // layer-2 y bf16 (peptide bf16 dead)
    unsigned short* yBl = Apl;
    float* H   = xp;                    // attention pre-act (xp dead after last gru)
    float* ctx = (float*)yAh;           // ctx [CB,512] f32 (yAh dead after score GEMM)

    const int M = (int)CB * TT;
    dim3 pb(256), pg768(6, M / 128), pg512(4, M / 128);
    dim3 gb(256), gg((unsigned)CB / GRU_ROWS);
    dim3 cab(256);

    for (int c = 0; c < NC; ++c) {
        const float* pep_c = peptide + (size_t)c * CB * TT * 553;
        const float* hid_c = hidden + (size_t)c * CB * 256;
        float* logits_c = out + (size_t)c * CB * 2;
        float* att_c    = out + 8192 + (size_t)c * CB * TT;

        // ---- layer 1 (K=553 -> Kp=576, h0 = hidden, both dirs share A) ----
        cvta_kernel<<<dim3(2048), cab, 0, stream>>>(pep_c, Aph, Apl, 553, 576, (unsigned)M * 576u);
        cvtu_kernel<<<dim3(384), cab, 0, stream>>>(gU[0], Upf);
        cvtu_kernel<<<dim3(384), cab, 0, stream>>>(gU[1], Upb);
        cvtw_kernel<<<dim3(3, 576), cab, 0, stream>>>(gW[0], Wth, Wtl, 553, 576, 768);
        projm_kernel<<<pg768, pb, 0, stream>>>(Aph, Apl, Wth, Wtl, gB[0], xp, 576, 768);
        gru_kernel<<<gg, gb, 0, stream>>>(xp, Upf, gB[0], hid_c, yAf, yAh, yAl, 0, 0);
        cvtw_kernel<<<dim3(3, 576), cab, 0, stream>>>(gW[1], Wth, Wtl, 553, 576, 768);
        projm_kernel<<<pg768, pb, 0, stream>>>(Aph, Apl, Wth, Wtl, gB[1], xp, 576, 768);
        gru_kernel<<<gg, gb, 0, stream>>>(xp, Upb, gB[1], hid_c, yAf, yAh, yAl, 256, 1);
        // peptide bf16 (Aph/Apl) dead; region reused as yBh/yBl.

        // ---- layer 2 (K=512, h0 = 0); A = layer-1 y bf16 ----
        cvtu_kernel<<<dim3(384), cab, 0, stream>>>(gU[2], Upf);
        cvtu_kernel<<<dim3(384), cab, 0, stream>>>(gU[3], Upb);
        cvtw_kernel<<<dim3(3, 512), cab, 0, stream>>>(gW[2], Wth, Wtl, 512, 512, 768);
        projm_kernel<<<pg768, pb, 0, stream>>>(yAh, yAl, Wth, Wtl, gB[2], xp, 512, 768);
        gru_kernel<<<gg, gb, 0, stream>>>(xp, Upf, gB[2], nullptr, yAf, yBh, yBl, 0, 0);
        cvtw_kernel<<<dim3(3, 512), cab, 0, stream>>>(gW[3], Wth, Wtl, 512, 512, 768);
        projm_kernel<<<pg768, pb, 0, stream>>>(yAh, yAl, Wth, Wtl, gB[3], xp, 512, 768);
        gru_kernel<<<gg, gb, 0, stream>>>(xp, Upb, gB[3], nullptr, yAf, yBh, yBl, 256, 1);

        // ---- layer 3; A = layer-2 y bf16; fp32 y survives for attention ----
        cvtu_kernel<<<dim3(384), cab, 0, stream>>>(gU[4], Upf);
        cvtu_kernel<<<dim3(384), cab, 0, stream>>>(gU[5], Upb);
        cvtw_kernel<<<dim3(3, 512), cab, 0, stream>>>(gW[4], Wth, Wtl, 512, 512, 768);
        projm_kernel<<<pg768, pb, 0, stream>>>(yBh, yBl, Wth, Wtl, gB[4], xp, 512, 768);
        gru_kernel<<<gg, gb, 0, stream>>>(xp, Upf, gB[4], nullptr, yAf, yAh, yAl, 0, 0);
        cvtw_kernel<<<dim3(3, 512), cab, 0, stream>>>(gW[5], Wth, Wtl, 512, 512, 768);
        projm_kernel<<<pg768, pb, 0, stream>>>(yBh, yBl, Wth, Wtl, gB[5], xp, 512, 768);
        gru_kernel<<<gg, gb, 0, stream>>>(xp, Upb, gB[5], nullptr, yAf, yAh, yAl, 256, 1);

        // ---- attention: H = Y@W1 + b1 (MFMA), then fused tanh/V/softmax/ctx ----
        cvtw_kernel<<<dim3(2, 512), cab, 0, stream>>>(att_W1, Wth, Wtl, 512, 512, 512);
        projm_kernel<<<pg512, pb, 0, stream>>>(yAh, yAl, Wth, Wtl, att_b1, H, 512, 512);
        tail_kernel<<<dim3((unsigned)CB), dim3(64), 0, stream>>>(H, yAf, att_V, att_bV, ctx, att_c);
        fc_kernel<<<dim3((unsigned)CB / 16), dim3(256), 0, stream>>>(ctx, fc1_W, fc1_b, fc2_W, fc2_b, logits_c);
    }
}

// Round 9
// 2434.026 us; speedup vs baseline: 2.3443x; 1.5148x over previous
//
#include <hip/hip_runtime.h>
#include <math.h>

#define TT 9

typedef __attribute__((ext_vector_type(8))) short bf16x8;
typedef __attribute__((ext_vector_type(4))) float f32x4;

__device__ __forceinline__ unsigned short f2bf(float x) {
    unsigned int u = __float_as_uint(x);
    unsigned int r = (u + 0x7fffu + ((u >> 16) & 1u)) >> 16;
    return (unsigned short)r;
}
__device__ __forceinline__ float bf2f(unsigned short h) {
    return __uint_as_float((unsigned int)h << 16);
}

// ============================================================================
// cvtA: peptide fp32 [rows,553] -> Ah,Al bf16 [rows,576], grid-stride.
// ============================================================================
__global__ __launch_bounds__(256) void cvta_kernel(
    const float* __restrict__ A, unsigned short* __restrict__ Ah,
    unsigned short* __restrict__ Al, int K, int Kp, unsigned total)
{
    for (unsigned idx = blockIdx.x * 256u + threadIdx.x; idx < total;
         idx += gridDim.x * 256u) {
        unsigned row = idx / (unsigned)Kp;
        unsigned k = idx - row * (unsigned)Kp;
        float v = (k < (unsigned)K) ? A[(size_t)row * K + k] : 0.f;
        unsigned short h = f2bf(v);
        unsigned short l = f2bf(v - bf2f(h));
        Ah[idx] = h;
        Al[idx] = l;
    }
}

// ============================================================================
// prep: ALL weight conversions in ONE launch (13 jobs via blockIdx.y).
// jobs 0..6: W -> hi/lo bf16 [N][Kp] transposed  (0,1:gW1 K=553 Kp=576 N=768;
//            2..5: gW2/3 K=Kp=512 N=768; 6: att_W1 K=Kp=512 N=512)
// jobs 7..12: U[256,768] -> MFMA-fragment-packed hi/lo bf16:
//            Upk[(kt*48+nt)*1024 + hl*512 + lane*8 + j],
//            k = kt*32+(lane>>4)*8+j, col = nt*16+(lane&15).
// ============================================================================
struct PrepPtrs { const float* w[7]; const float* u[6]; };

__global__ __launch_bounds__(256) void prep_kernel(
    PrepPtrs p, unsigned short* __restrict__ Wh, unsigned short* __restrict__ Wl,
    unsigned short* __restrict__ Upk)
{
    const int job = blockIdx.y;
    if (job < 7) {
        const int N  = (job == 6) ? 512 : 768;
        const int K  = (job < 2) ? 553 : 512;
        const int Kp = (job < 2) ? 576 : 512;
        const unsigned elems = (unsigned)N * Kp;
        unsigned short* wh = Wh + (size_t)job * 442368;
        unsigned short* wl = Wl + (size_t)job * 442368;
        for (unsigned idx = blockIdx.x * 256u + threadIdx.x; idx < elems;
             idx += gridDim.x * 256u) {
            unsigned n = idx / (unsigned)Kp;
            unsigned k = idx - n * (unsigned)Kp;
            float v = (k < (unsigned)K) ? p.w[job][(size_t)k * N + n] : 0.f;
            unsigned short h = f2bf(v);
            wh[idx] = h;
            wl[idx] = f2bf(v - bf2f(h));
        }
    } else {
        const int ju = job - 7;
        unsigned short* up = Upk + (size_t)ju * 393216;
        const float* U = p.u[ju];
        for (unsigned idx = blockIdx.x * 256u + threadIdx.x; idx < 196608u;
             idx += gridDim.x * 256u) {
            unsigned j = idx & 7u;
            unsigned l = (idx >> 3) & 63u;
            unsigned blk = idx >> 9;           // kt*48+nt
            unsigned k   = (blk / 48u) * 32u + ((l >> 4) << 3) + j;
            unsigned col = (blk % 48u) * 16u + (l & 15u);
            float v = U[(size_t)k * 768 + col];
            unsigned short h = f2bf(v);
            up[(size_t)blk * 1024 + l * 8 + j]       = h;
            up[(size_t)blk * 1024 + 512 + l * 8 + j] = f2bf(v - bf2f(h));
        }
    }
}

// ============================================================================
// projm: C[M,N] = A@W + b via split-bf16 MFMA (unchanged from r7).
// ============================================================================
__global__ __launch_bounds__(256) void projm_kernel(
    const unsigned short* __restrict__ Ah, const unsigned short* __restrict__ Al,
    const unsigned short* __restrict__ Wh, const unsigned short* __restrict__ Wl,
    const float* __restrict__ bs, float* __restrict__ C, int Kp, int N)
{
    __shared__ unsigned short Ah_s[128][40];
    __shared__ unsigned short Al_s[128][40];
    __shared__ unsigned short Wh_s[128][40];
    __shared__ unsigned short Wl_s[128][40];

    const int tid = threadIdx.x;
    const int m0 = blockIdx.y * 128;
    const int n0 = blockIdx.x * 128;

    const int srow = tid >> 1;
    const int skh  = (tid & 1) * 16;

    const unsigned short* pAh = Ah + (size_t)(m0 + srow) * Kp + skh;
    const unsigned short* pAl = Al + (size_t)(m0 + srow) * Kp + skh;
    const unsigned short* pWh = Wh + (size_t)(n0 + srow) * Kp + skh;
    const unsigned short* pWl = Wl + (size_t)(n0 + srow) * Kp + skh;

    const int w    = tid >> 6;
    const int wr   = (w >> 1) * 64;
    const int wc   = (w & 1) * 64;
    const int lane = tid & 63;
    const int lrow = lane & 15;
    const int kg8  = (lane >> 4) * 8;

    f32x4 acc[4][4];
    #pragma unroll
    for (int m = 0; m < 4; ++m)
        #pragma unroll
        for (int n = 0; n < 4; ++n)
            acc[m][n] = (f32x4){0.f, 0.f, 0.f, 0.f};

    uint4 rAh0 = *(const uint4*)(pAh), rAh1 = *(const uint4*)(pAh + 8);
    uint4 rAl0 = *(const uint4*)(pAl), rAl1 = *(const uint4*)(pAl + 8);
    uint4 rWh0 = *(const uint4*)(pWh), rWh1 = *(const uint4*)(pWh + 8);
    uint4 rWl0 = *(const uint4*)(pWl), rWl1 = *(const uint4*)(pWl + 8);
    pAh += 32; pAl += 32; pWh += 32; pWl += 32;

    const int nsteps = Kp >> 5;
    for (int s = 0; s < nsteps; ++s) {
        __syncthreads();
        *(uint4*)&Ah_s[srow][skh]     = rAh0;
        *(uint4*)&Ah_s[srow][skh + 8] = rAh1;
        *(uint4*)&Al_s[srow][skh]     = rAl0;
        *(uint4*)&Al_s[srow][skh + 8] = rAl1;
        *(uint4*)&Wh_s[srow][skh]     = rWh0;
        *(uint4*)&Wh_s[srow][skh + 8] = rWh1;
        *(uint4*)&Wl_s[srow][skh]     = rWl0;
        *(uint4*)&Wl_s[srow][skh + 8] = rWl1;
        __syncthreads();

        if (s + 1 < nsteps) {
            rAh0 = *(const uint4*)(pAh); rAh1 = *(const uint4*)(pAh + 8);
            rAl0 = *(const uint4*)(pAl); rAl1 = *(const uint4*)(pAl + 8);
            rWh0 = *(const uint4*)(pWh); rWh1 = *(const uint4*)(pWh + 8);
            rWl0 = *(const uint4*)(pWl); rWl1 = *(const uint4*)(pWl + 8);
            pAh += 32; pAl += 32; pWh += 32; pWl += 32;
        }

        bf16x8 fa_h[4], fa_l[4], fb_h[4], fb_l[4];
        #pragma unroll
        for (int m = 0; m < 4; ++m) {
            fa_h[m] = *(const bf16x8*)&Ah_s[wr + m * 16 + lrow][kg8];
            fa_l[m] = *(const bf16x8*)&Al_s[wr + m * 16 + lrow][kg8];
        }
        #pragma unroll
        for (int n = 0; n < 4; ++n) {
            fb_h[n] = *(const bf16x8*)&Wh_s[wc + n * 16 + lrow][kg8];
            fb_l[n] = *(const bf16x8*)&Wl_s[wc + n * 16 + lrow][kg8];
        }
        #pragma unroll
        for (int m = 0; m < 4; ++m)
            #pragma unroll
            for (int n = 0; n < 4; ++n) {
                acc[m][n] = __builtin_amdgcn_mfma_f32_16x16x32_bf16(fa_h[m], fb_h[n], acc[m][n], 0, 0, 0);
                acc[m][n] = __builtin_amdgcn_mfma_f32_16x16x32_bf16(fa_h[m], fb_l[n], acc[m][n], 0, 0, 0);
                acc[m][n] = __builtin_amdgcn_mfma_f32_16x16x32_bf16(fa_l[m], fb_h[n], acc[m][n], 0, 0, 0);
            }
    }

    const int orow = (lane >> 4) * 4;
    const int ocol = lane & 15;
    #pragma unroll
    for (int n = 0; n < 4; ++n) {
        const int col = n0 + wc + n * 16 + ocol;
        const float bn = bs[col];
        #pragma unroll
        for (int m = 0; m < 4; ++m) {
            const int rbase = m0 + wr + m * 16 + orow;
            #pragma unroll
            for (int r = 0; r < 4; ++r)
                C[(size_t)(rbase + r) * N + col] = acc[m][n][r] + bn;
        }
    }
}

// ============================================================================
// gru_mfma: persistent-h, 16 rows/block, 4 waves. h@U on the MATRIX pipe via
// split-bf16 (h hi/lo x U hi/lo, 3 terms). U pre-packed in fragment layout
// (prep jobs 7-12): wave w owns N-tiles w*12..w*12+11. Gate preacts round-trip
// through LDS in two 8-row halves (fits 64KB static LDS with h).
// Emits y as hi/lo bf16 only (fp32 y reconstructed downstream as hi+lo).
// ============================================================================
__global__ __launch_bounds__(256) void gru_mfma_kernel(
    const float* __restrict__ xp, const unsigned short* __restrict__ Upk,
    const float* __restrict__ b, const float* __restrict__ h0,
    unsigned short* __restrict__ yh, unsigned short* __restrict__ yl,
    int out_off, int dir)
{
    __shared__ float h[16][272];    // padded: stride 272 => 2-way (free) on A-build
    __shared__ float g8[8][772];    // half-tile gate preacts, padded

    const int tid  = threadIdx.x;
    const int lane = tid & 63;
    const int w    = tid >> 6;
    const int lrow = lane & 15;
    const int lk8  = (lane >> 4) * 8;
    const int r0   = blockIdx.x * 16;

    #pragma unroll
    for (int i = 0; i < 16; ++i)
        h[i][tid] = h0 ? h0[(size_t)(r0 + i) * 256 + tid] : 0.f;

    const float bz = b[768 + tid], br = b[768 + 256 + tid], bhv = b[768 + 512 + tid];
    __syncthreads();

    for (int t = 0; t < TT; ++t) {
        const int te = dir ? (TT - 1 - t) : t;

        f32x4 acc[12];
        #pragma unroll
        for (int j = 0; j < 12; ++j) acc[j] = (f32x4){0.f, 0.f, 0.f, 0.f};

        for (int kt = 0; kt < 8; ++kt) {
            // A fragment: h[lrow][kt*32+lk8 .. +8] -> hi/lo bf16
            float4 a0 = *(const float4*)&h[lrow][kt * 32 + lk8];
            float4 a1 = *(const float4*)&h[lrow][kt * 32 + lk8 + 4];
            float av[8] = {a0.x, a0.y, a0.z, a0.w, a1.x, a1.y, a1.z, a1.w};
            bf16x8 ah, al;
            #pragma unroll
            for (int e = 0; e < 8; ++e) {
                unsigned short hi = f2bf(av[e]);
                ah[e] = (short)hi;
                al[e] = (short)f2bf(av[e] - bf2f(hi));
            }
            #pragma unroll
            for (int j = 0; j < 12; ++j) {
                const int ntg = w * 12 + j;
                const unsigned short* fb = Upk + ((size_t)(kt * 48 + ntg)) * 1024 + lane * 8;
                bf16x8 bh = *(const bf16x8*)(fb);
                bf16x8 bl = *(const bf16x8*)(fb + 512);
                acc[j] = __builtin_amdgcn_mfma_f32_16x16x32_bf16(ah, bh, acc[j], 0, 0, 0);
                acc[j] = __builtin_amdgcn_mfma_f32_16x16x32_bf16(ah, bl, acc[j], 0, 0, 0);
                acc[j] = __builtin_amdgcn_mfma_f32_16x16x32_bf16(al, bh, acc[j], 0, 0, 0);
            }
        }

        // ---- half 1: rows 0-7 (acc rows live in lanes 0-31) ----
        if (lane < 32) {
            const int rowb = (lane >> 4) * 4;   // 0 or 4
            #pragma unroll
            for (int j = 0; j < 12; ++j) {
                const int col = w * 192 + j * 16 + lrow;
                #pragma unroll
                for (int r = 0; r < 4; ++r)
                    g8[rowb + r][col] = acc[j][r];
            }
        }
        __syncthreads();   // g half ready; all h reads of this timestep done
        #pragma unroll
        for (int i = 0; i < 8; ++i) {
            const size_t xb = ((size_t)(r0 + i) * TT + te) * 768;
            float xz = xp[xb + tid];
            float xr = xp[xb + tid + 256];
            float xh = xp[xb + tid + 512];
            float z  = 1.f / (1.f + expf(-(xz + g8[i][tid] + bz)));
            float r_ = 1.f / (1.f + expf(-(xr + g8[i][tid + 256] + br)));
            float hh = tanhf(xh + r_ * (g8[i][tid + 512] + bhv));
            float hn = z * h[i][tid] + (1.f - z) * hh;
            h[i][tid] = hn;
            const size_t yi = ((size_t)(r0 + i) * TT + te) * 512 + out_off + tid;
            unsigned short hb = f2bf(hn);
            yh[yi] = hb;
            yl[yi] = f2bf(hn - bf2f(hb));
        }
        __syncthreads();   // rows 0-7 done reading g8

        // ---- half 2: rows 8-15 (acc rows live in lanes 32-63) ----
        if (lane >= 32) {
            const int rowb = ((lane >> 4) - 2) * 4;  // 0 or 4
            #pragma unroll
            for (int j = 0; j < 12; ++j) {
                const int col = w * 192 + j * 16 + lrow;
                #pragma unroll
                for (int r = 0; r < 4; ++r)
                    g8[rowb + r][col] = acc[j][r];
            }
        }
        __syncthreads();
        #pragma unroll
        for (int i = 0; i < 8; ++i) {
            const int row = i + 8;
            const size_t xb = ((size_t)(r0 + row) * TT + te) * 768;
            float xz = xp[xb + tid];
            float xr = xp[xb + tid + 256];
            float xh = xp[xb + tid + 512];
            float z  = 1.f / (1.f + expf(-(xz + g8[i][tid] + bz)));
            float r_ = 1.f / (1.f + expf(-(xr + g8[i][tid + 256] + br)));
            float hh = tanhf(xh + r_ * (g8[i][tid + 512] + bhv));
            float hn = z * h[row][tid] + (1.f - z) * hh;
            h[row][tid] = hn;
            const size_t yi = ((size_t)(r0 + row) * TT + te) * 512 + out_off + tid;
            unsigned short hb = f2bf(hn);
            yh[yi] = hb;
            yl[yi] = f2bf(hn - bf2f(hb));
        }
        __syncthreads();   // h fully updated before next timestep's A-build
    }
}

// ============================================================================
// tail: per batch row (64 lanes): score from H, softmax over T, att write,
// ctx = sum w_t * Y where Y is reconstructed hi+lo.
// ============================================================================
__global__ __launch_bounds__(64) void tail_kernel(
    const float* __restrict__ H, const unsigned short* __restrict__ Yh,
    const unsigned short* __restrict__ Yl,
    const float* __restrict__ V, const float* __restrict__ bV,
    float* __restrict__ ctx, float* __restrict__ att)
{
    const int b = blockIdx.x;
    const int lane = threadIdx.x;

    float sc[TT];
    #pragma unroll
    for (int t = 0; t < TT; ++t) {
        const float* Hp = H + ((size_t)b * TT + t) * 512;
        float s = 0.f;
        #pragma unroll
        for (int j = 0; j < 8; ++j) {
            int cix = lane + j * 64;
            s = fmaf(tanhf(Hp[cix]), V[cix], s);
        }
        #pragma unroll
        for (int off = 32; off > 0; off >>= 1) s += __shfl_xor(s, off);
        sc[t] = s + bV[0];
    }
    float m = sc[0];
    #pragma unroll
    for (int t = 1; t < TT; ++t) m = fmaxf(m, sc[t]);
    float sum = 0.f;
    float wt[TT];
    #pragma unroll
    for (int t = 0; t < TT; ++t) { wt[t] = expf(sc[t] - m); sum += wt[t]; }
    const float inv = 1.f / sum;
    #pragma unroll
    for (int t = 0; t < TT; ++t) {
        wt[t] *= inv;
        if (lane == t) att[(size_t)b * TT + t] = wt[t];
    }
    #pragma unroll
    for (int j = 0; j < 8; ++j) {
        int cix = lane + j * 64;
        float a = 0.f;
        #pragma unroll
        for (int t = 0; t < TT; ++t) {
            size_t yi = ((size_t)b * TT + t) * 512 + cix;
            a = fmaf(wt[t], bf2f(Yh[yi]) + bf2f(Yl[yi]), a);
        }
        ctx[(size_t)b * 512 + cix] = a;
    }
}

// ============================================================================
// fused FC1(relu) + FC2 -> logits [rows,2] (unchanged)
// ============================================================================
__global__ __launch_bounds__(256) void fc_kernel(
    const float* __restrict__ ctx, const float* __restrict__ W1, const float* __restrict__ b1,
    const float* __restrict__ W2, const float* __restrict__ b2,
    float* __restrict__ logits)
{
    __shared__ float clds[16][512];
    const int tid = threadIdx.x;
    const int r0 = blockIdx.x * 16;
    for (int idx = tid; idx < 16 * 512; idx += 256)
        clds[idx >> 9][idx & 511] = ctx[(size_t)r0 * 512 + idx];
    __syncthreads();

    float acc0[16], acc1[16];
    #pragma unroll
    for (int i = 0; i < 16; ++i) { acc0[i] = 0.f; acc1[i] = 0.f; }

    for (int k = 0; k < 512; k += 8) {
        float w[8][2];
        #pragma unroll
        for (int kk = 0; kk < 8; ++kk) {
            const float* Wr = W1 + (size_t)(k + kk) * 512;
            w[kk][0] = Wr[tid];
            w[kk][1] = Wr[tid + 256];
        }
        #pragma unroll
        for (int i = 0; i < 16; ++i) {
            float4 y0 = *(const float4*)&clds[i][k];
            float4 y1 = *(const float4*)&clds[i][k + 4];
            float yv[8] = {y0.x, y0.y, y0.z, y0.w, y1.x, y1.y, y1.z, y1.w};
            float s0 = acc0[i], s1 = acc1[i];
            #pragma unroll
            for (int kk = 0; kk < 8; ++kk) {
                s0 = fmaf(yv[kk], w[kk][0], s0);
                s1 = fmaf(yv[kk], w[kk][1], s1);
            }
            acc0[i] = s0; acc1[i] = s1;
        }
    }
    const float w2a0 = W2[(size_t)tid * 2],         w2a1 = W2[(size_t)tid * 2 + 1];
    const float w2b0 = W2[(size_t)(tid + 256) * 2], w2b1 = W2[(size_t)(tid + 256) * 2 + 1];
    const float c0 = b1[tid], c1 = b1[tid + 256];
    __syncthreads();
    #pragma unroll
    for (int i = 0; i < 16; ++i) {
        float h0v = fmaxf(acc0[i] + c0, 0.f);
        float h1v = fmaxf(acc1[i] + c1, 0.f);
        clds[i][tid * 2]     = fmaf(h0v, w2a0, h1v * w2b0);
        clds[i][tid * 2 + 1] = fmaf(h0v, w2a1, h1v * w2b1);
    }
    __syncthreads();
    const int wave = tid >> 6, lane = tid & 63;
    for (int i = wave * 4; i < wave * 4 + 4; ++i) {
        float px = clds[i][lane * 2]     + clds[i][(lane + 64) * 2]     + clds[i][(lane + 128) * 2]     + clds[i][(lane + 192) * 2];
        float py = clds[i][lane * 2 + 1] + clds[i][(lane + 64) * 2 + 1] + clds[i][(lane + 128) * 2 + 1] + clds[i][(lane + 192) * 2 + 1];
        #pragma unroll
        for (int off = 32; off > 0; off >>= 1) { px += __shfl_down(px, off); py += __shfl_down(py, off); }
        if (lane == 0) {
            logits[(size_t)(r0 + i) * 2]     = px + b2[0];
            logits[(size_t)(r0 + i) * 2 + 1] = py + b2[1];
        }
    }
}

// ============================================================================
extern "C" void kernel_launch(void* const* d_in, const int* in_sizes, int n_in,
                              void* d_out, int out_size, void* d_ws, size_t ws_size,
                              hipStream_t stream)
{
    const float* peptide = (const float*)d_in[0];
    const float* hidden  = (const float*)d_in[1];
    const float* gW[6] = { (const float*)d_in[2],  (const float*)d_in[5],
                           (const float*)d_in[8],  (const float*)d_in[11],
                           (const float*)d_in[14], (const float*)d_in[17] };
    const float* gU[6] = { (const float*)d_in[3],  (const float*)d_in[6],
                           (const float*)d_in[9],  (const float*)d_in[12],
                           (const float*)d_in[15], (const float*)d_in[18] };
    const float* gB[6] = { (const float*)d_in[4],  (const float*)d_in[7],
                           (const float*)d_in[10], (const float*)d_in[13],
                           (const float*)d_in[16], (const float*)d_in[19] };
    const float* att_W1 = (const float*)d_in[20];
    const float* att_b1 = (const float*)d_in[21];
    const float* att_V  = (const float*)d_in[22];
    const float* att_bV = (const float*)d_in[23];
    const float* fc1_W = (const float*)d_in[24];
    const float* fc1_b = (const float*)d_in[25];
    const float* fc2_W = (const float*)d_in[26];
    const float* fc2_b = (const float*)d_in[27];

    float* out = (float*)d_out;   // [0,8192) logits, [8192,45056) attention weights

    // Workspace per chunk (bytes): xp f32 + yAh/yAl bf16 + Aph/Apl bf16
    //  + W hi/lo (7 jobs) + Upk (6 packed U).
    const size_t WJOB = 442368;            // per-job W elems (max)
    const size_t UJOB = 393216;            // per-U packed elems (hi+lo)
    int NC = 1;
    size_t CB = 4096;
    for (; NC <= 32; NC *= 2) {
        CB = 4096 / NC;
        size_t bytes = (size_t)CB * TT * 768 * 4
                     + 2 * (size_t)CB * TT * 512 * 2
                     + 2 * (size_t)CB * TT * 576 * 2
                     + 2 * 7 * WJOB * 2 + 6 * UJOB * 2;
        if (bytes <= ws_size) break;
    }
    if (NC > 32) { NC = 32; CB = 128; }

    char* ws = (char*)d_ws;
    float* xp  = (float*)ws;                                  ws += (size_t)CB * TT * 768 * 4;
    unsigned short* yAh = (unsigned short*)ws;                ws += (size_t)CB * TT * 512 * 2;
    unsigned short* yAl = (unsigned short*)ws;                ws += (size_t)CB * TT * 512 * 2;
    unsigned short* Aph = (unsigned short*)ws;                ws += (size_t)CB * TT * 576 * 2;
    unsigned short* Apl = (unsigned short*)ws;                ws += (size_t)CB * TT * 576 * 2;
    unsigned short* Wh  = (unsigned short*)ws;                ws += 7 * WJOB * 2;
    unsigned short* Wl  = (unsigned short*)ws;                ws += 7 * WJOB * 2;
    unsigned short* Upk = (unsigned short*)ws;
    // aliases:
    unsigned short* yBh = Aph;          // layer-2 y bf16 (peptide bf16 dead)
    unsigned short* yBl = Apl;
    float* H   = xp;                    // attention preact (xp dead after last gru)
    float* ctx = (float*)Aph;           // ctx f32 (yBh dead after layer-3 projm)

    const int M = (int)CB * TT;
    dim3 pb(256), pg768(6, M / 128), pg512(4, M / 128);
    dim3 gb(256), gg((unsigned)CB / 16);
    dim3 cab(256);

    // ---- one-shot weight prep (13 jobs fused) ----
    PrepPtrs pp;
    for (int i = 0; i < 6; ++i) { pp.w[i] = gW[i]; pp.u[i] = gU[i]; }
    pp.w[6] = att_W1;
    prep_kernel<<<dim3(1728, 13), cab, 0, stream>>>(pp, Wh, Wl, Upk);

    for (int c = 0; c < NC; ++c) {
        const float* pep_c = peptide + (size_t)c * CB * TT * 553;
        const float* hid_c = hidden + (size_t)c * CB * 256;
        float* logits_c = out + (size_t)c * CB * 2;
        float* att_c    = out + 8192 + (size_t)c * CB * TT;

        // ---- layer 1 (Kp=576, h0 = hidden, both dirs share peptide bf16) ----
        cvta_kernel<<<dim3(2048), cab, 0, stream>>>(pep_c, Aph, Apl, 553, 576, (unsigned)M * 576u);
        projm_kernel<<<pg768, pb, 0, stream>>>(Aph, Apl, Wh + 0 * WJOB, Wl + 0 * WJOB, gB[0], xp, 576, 768);
        gru_mfma_kernel<<<gg, gb, 0, stream>>>(xp, Upk + 0 * UJOB, gB[0], hid_c, yAh, yAl, 0, 0);
        projm_kernel<<<pg768, pb, 0, stream>>>(Aph, Apl, Wh + 1 * WJOB, Wl + 1 * WJOB, gB[1], xp, 576, 768);
        gru_mfma_kernel<<<gg, gb, 0, stream>>>(xp, Upk + 1 * UJOB, gB[1], hid_c, yAh, yAl, 256, 1);
        // peptide bf16 dead; region reused as yBh/yBl.

        // ---- layer 2 (Kp=512, h0 = 0); A = layer-1 y bf16 ----
        projm_kernel<<<pg768, pb, 0, stream>>>(yAh, yAl, Wh + 2 * WJOB, Wl + 2 * WJOB, gB[2], xp, 512, 768);
        gru_mfma_kernel<<<gg, gb, 0, stream>>>(xp, Upk + 2 * UJOB, gB[2], nullptr, yBh, yBl, 0, 0);
        projm_kernel<<<pg768, pb, 0, stream>>>(yAh, yAl, Wh + 3 * WJOB, Wl + 3 * WJOB, gB[3], xp, 512, 768);
        gru_mfma_kernel<<<gg, gb, 0, stream>>>(xp, Upk + 3 * UJOB, gB[3], nullptr, yBh, yBl, 256, 1);

        // ---- layer 3; A = layer-2 y bf16 ----
        projm_kernel<<<pg768, pb, 0, stream>>>(yBh, yBl, Wh + 4 * WJOB, Wl + 4 * WJOB, gB[4], xp, 512, 768);
        gru_mfma_kernel<<<gg, gb, 0, stream>>>(xp, Upk + 4 * UJOB, gB[4], nullptr, yAh, yAl, 0, 0);
        projm_kernel<<<pg768, pb, 0, stream>>>(yBh, yBl, Wh + 5 * WJOB, Wl + 5 * WJOB, gB[5], xp, 512, 768);
        gru_mfma_kernel<<<gg, gb, 0, stream>>>(xp, Upk + 5 * UJOB, gB[5], nullptr, yAh, yAl, 256, 1);

        // ---- attention: H = Y@W1 + b1 (MFMA), fused tanh/V/softmax/ctx, head ----
        projm_kernel<<<pg512, pb, 0, stream>>>(yAh, yAl, Wh + 6 * WJOB, Wl + 6 * WJOB, att_b1, H, 512, 512);
        tail_kernel<<<dim3((unsigned)CB), dim3(64), 0, stream>>>(H, yAh, yAl, att_V, att_bV, ctx, att_c);
        fc_kernel<<<dim3((unsigned)CB / 16), dim3(256), 0, stream>>>(ctx, fc1_W, fc1_b, fc2_W, fc2_b, logits_c);
    }
}

// Round 10
// 2050.180 us; speedup vs baseline: 2.7832x; 1.1872x over previous
//
#include <hip/hip_runtime.h>
#include <math.h>

#define TT 9

typedef __attribute__((ext_vector_type(8))) short bf16x8;
typedef __attribute__((ext_vector_type(4))) float f32x4;

__device__ __forceinline__ unsigned short f2bf(float x) {
    unsigned int u = __float_as_uint(x);
    unsigned int r = (u + 0x7fffu + ((u >> 16) & 1u)) >> 16;
    return (unsigned short)r;
}
__device__ __forceinline__ float bf2f(unsigned short h) {
    return __uint_as_float((unsigned int)h << 16);
}

// ============================================================================
// cvtA: peptide fp32 [rows,553] -> Ah,Al bf16 [rows,576], grid-stride.
// ============================================================================
__global__ __launch_bounds__(256) void cvta_kernel(
    const float* __restrict__ A, unsigned short* __restrict__ Ah,
    unsigned short* __restrict__ Al, int K, int Kp, unsigned total)
{
    for (unsigned idx = blockIdx.x * 256u + threadIdx.x; idx < total;
         idx += gridDim.x * 256u) {
        unsigned row = idx / (unsigned)Kp;
        unsigned k = idx - row * (unsigned)Kp;
        float v = (k < (unsigned)K) ? A[(size_t)row * K + k] : 0.f;
        unsigned short h = f2bf(v);
        unsigned short l = f2bf(v - bf2f(h));
        Ah[idx] = h;
        Al[idx] = l;
    }
}

// ============================================================================
// prep: ALL weight conversions in ONE launch (13 jobs via blockIdx.y).
// jobs 0..6: W -> hi/lo bf16 [N][Kp] transposed. jobs 7..12: U -> MFMA
// fragment-packed hi/lo (same layout as rounds 8-9, HW-verified).
// ============================================================================
struct PrepPtrs { const float* w[7]; const float* u[6]; };

__global__ __launch_bounds__(256) void prep_kernel(
    PrepPtrs p, unsigned short* __restrict__ Wh, unsigned short* __restrict__ Wl,
    unsigned short* __restrict__ Upk)
{
    const int job = blockIdx.y;
    if (job < 7) {
        const int N  = (job == 6) ? 512 : 768;
        const int K  = (job < 2) ? 553 : 512;
        const int Kp = (job < 2) ? 576 : 512;
        const unsigned elems = (unsigned)N * Kp;
        unsigned short* wh = Wh + (size_t)job * 442368;
        unsigned short* wl = Wl + (size_t)job * 442368;
        for (unsigned idx = blockIdx.x * 256u + threadIdx.x; idx < elems;
             idx += gridDim.x * 256u) {
            unsigned n = idx / (unsigned)Kp;
            unsigned k = idx - n * (unsigned)Kp;
            float v = (k < (unsigned)K) ? p.w[job][(size_t)k * N + n] : 0.f;
            unsigned short h = f2bf(v);
            wh[idx] = h;
            wl[idx] = f2bf(v - bf2f(h));
        }
    } else {
        const int ju = job - 7;
        unsigned short* up = Upk + (size_t)ju * 393216;
        const float* U = p.u[ju];
        for (unsigned idx = blockIdx.x * 256u + threadIdx.x; idx < 196608u;
             idx += gridDim.x * 256u) {
            unsigned j = idx & 7u;
            unsigned l = (idx >> 3) & 63u;
            unsigned blk = idx >> 9;           // kt*48+nt
            unsigned k   = (blk / 48u) * 32u + ((l >> 4) << 3) + j;
            unsigned col = (blk % 48u) * 16u + (l & 15u);
            float v = U[(size_t)k * 768 + col];
            unsigned short h = f2bf(v);
            up[(size_t)blk * 1024 + l * 8 + j]       = h;
            up[(size_t)blk * 1024 + 512 + l * 8 + j] = f2bf(v - bf2f(h));
        }
    }
}

// ============================================================================
// projm: C = A@W + b via split-bf16 MFMA, BOTH directions in one launch
// (blockIdx.z selects W/bias/C set). Internals unchanged from r7-r9.
// ============================================================================
__global__ __launch_bounds__(256) void projm_kernel(
    const unsigned short* __restrict__ Ah, const unsigned short* __restrict__ Al,
    const unsigned short* __restrict__ Wh0, const unsigned short* __restrict__ Wl0,
    const float* __restrict__ b0, float* __restrict__ C0,
    const unsigned short* __restrict__ Wh1, const unsigned short* __restrict__ Wl1,
    const float* __restrict__ b1, float* __restrict__ C1,
    int Kp, int N)
{
    const unsigned short* Wh = blockIdx.z ? Wh1 : Wh0;
    const unsigned short* Wl = blockIdx.z ? Wl1 : Wl0;
    const float* bs = blockIdx.z ? b1 : b0;
    float* C = blockIdx.z ? C1 : C0;

    __shared__ unsigned short Ah_s[128][40];
    __shared__ unsigned short Al_s[128][40];
    __shared__ unsigned short Wh_s[128][40];
    __shared__ unsigned short Wl_s[128][40];

    const int tid = threadIdx.x;
    const int m0 = blockIdx.y * 128;
    const int n0 = blockIdx.x * 128;

    const int srow = tid >> 1;
    const int skh  = (tid & 1) * 16;

    const unsigned short* pAh = Ah + (size_t)(m0 + srow) * Kp + skh;
    const unsigned short* pAl = Al + (size_t)(m0 + srow) * Kp + skh;
    const unsigned short* pWh = Wh + (size_t)(n0 + srow) * Kp + skh;
    const unsigned short* pWl = Wl + (size_t)(n0 + srow) * Kp + skh;

    const int w    = tid >> 6;
    const int wr   = (w >> 1) * 64;
    const int wc   = (w & 1) * 64;
    const int lane = tid & 63;
    const int lrow = lane & 15;
    const int kg8  = (lane >> 4) * 8;

    f32x4 acc[4][4];
    #pragma unroll
    for (int m = 0; m < 4; ++m)
        #pragma unroll
        for (int n = 0; n < 4; ++n)
            acc[m][n] = (f32x4){0.f, 0.f, 0.f, 0.f};

    uint4 rAh0 = *(const uint4*)(pAh), rAh1 = *(const uint4*)(pAh + 8);
    uint4 rAl0 = *(const uint4*)(pAl), rAl1 = *(const uint4*)(pAl + 8);
    uint4 rWh0 = *(const uint4*)(pWh), rWh1 = *(const uint4*)(pWh + 8);
    uint4 rWl0 = *(const uint4*)(pWl), rWl1 = *(const uint4*)(pWl + 8);
    pAh += 32; pAl += 32; pWh += 32; pWl += 32;

    const int nsteps = Kp >> 5;
    for (int s = 0; s < nsteps; ++s) {
        __syncthreads();
        *(uint4*)&Ah_s[srow][skh]     = rAh0;
        *(uint4*)&Ah_s[srow][skh + 8] = rAh1;
        *(uint4*)&Al_s[srow][skh]     = rAl0;
        *(uint4*)&Al_s[srow][skh + 8] = rAl1;
        *(uint4*)&Wh_s[srow][skh]     = rWh0;
        *(uint4*)&Wh_s[srow][skh + 8] = rWh1;
        *(uint4*)&Wl_s[srow][skh]     = rWl0;
        *(uint4*)&Wl_s[srow][skh + 8] = rWl1;
        __syncthreads();

        if (s + 1 < nsteps) {
            rAh0 = *(const uint4*)(pAh); rAh1 = *(const uint4*)(pAh + 8);
            rAl0 = *(const uint4*)(pAl); rAl1 = *(const uint4*)(pAl + 8);
            rWh0 = *(const uint4*)(pWh); rWh1 = *(const uint4*)(pWh + 8);
            rWl0 = *(const uint4*)(pWl); rWl1 = *(const uint4*)(pWl + 8);
            pAh += 32; pAl += 32; pWh += 32; pWl += 32;
        }

        bf16x8 fa_h[4], fa_l[4], fb_h[4], fb_l[4];
        #pragma unroll
        for (int m = 0; m < 4; ++m) {
            fa_h[m] = *(const bf16x8*)&Ah_s[wr + m * 16 + lrow][kg8];
            fa_l[m] = *(const bf16x8*)&Al_s[wr + m * 16 + lrow][kg8];
        }
        #pragma unroll
        for (int n = 0; n < 4; ++n) {
            fb_h[n] = *(const bf16x8*)&Wh_s[wc + n * 16 + lrow][kg8];
            fb_l[n] = *(const bf16x8*)&Wl_s[wc + n * 16 + lrow][kg8];
        }
        #pragma unroll
        for (int m = 0; m < 4; ++m)
            #pragma unroll
            for (int n = 0; n < 4; ++n) {
                acc[m][n] = __builtin_amdgcn_mfma_f32_16x16x32_bf16(fa_h[m], fb_h[n], acc[m][n], 0, 0, 0);
                acc[m][n] = __builtin_amdgcn_mfma_f32_16x16x32_bf16(fa_h[m], fb_l[n], acc[m][n], 0, 0, 0);
                acc[m][n] = __builtin_amdgcn_mfma_f32_16x16x32_bf16(fa_l[m], fb_h[n], acc[m][n], 0, 0, 0);
            }
    }

    const int orow = (lane >> 4) * 4;
    const int ocol = lane & 15;
    #pragma unroll
    for (int n = 0; n < 4; ++n) {
        const int col = n0 + wc + n * 16 + ocol;
        const float bn = bs[col];
        #pragma unroll
        for (int m = 0; m < 4; ++m) {
            const int rbase = m0 + wr + m * 16 + orow;
            #pragma unroll
            for (int r = 0; r < 4; ++r)
                C[(size_t)(rbase + r) * N + col] = acc[m][n][r] + bn;
        }
    }
}

// ============================================================================
// gru helpers: U-fragment group load (6 N-tiles x hi/lo) and MFMA group.
// ============================================================================
__device__ __forceinline__ void load_group(const unsigned short* __restrict__ base,
                                           bf16x8* buf)
{
    #pragma unroll
    for (int jj = 0; jj < 6; ++jj) {
        buf[jj * 2]     = *(const bf16x8*)(base + (size_t)jj * 1024);
        buf[jj * 2 + 1] = *(const bf16x8*)(base + (size_t)jj * 1024 + 512);
    }
}

__device__ __forceinline__ void mfma_group(const bf16x8& ah, const bf16x8& al,
                                           const bf16x8* buf, f32x4* accg)
{
    #pragma unroll
    for (int jj = 0; jj < 6; ++jj) {
        accg[jj] = __builtin_amdgcn_mfma_f32_16x16x32_bf16(ah, buf[jj * 2],     accg[jj], 0, 0, 0);
        accg[jj] = __builtin_amdgcn_mfma_f32_16x16x32_bf16(ah, buf[jj * 2 + 1], accg[jj], 0, 0, 0);
        accg[jj] = __builtin_amdgcn_mfma_f32_16x16x32_bf16(al, buf[jj * 2],     accg[jj], 0, 0, 0);
    }
}

// ============================================================================
// gru_mfma: persistent-h, 16 rows/block, BOTH directions in one launch
// (blockIdx.y = dir -> 2 blocks/CU, 2 waves/SIMD). h@U on the matrix pipe
// via split-bf16; U fragments register double-buffered (groups of 6 tiles)
// so 12 L2 loads stay in flight under each 18-MFMA cluster; xp gate inputs
// prefetched at timestep start (2 halves of 24 loads, vmcnt<=48).
// ============================================================================
__global__ __launch_bounds__(256, 2) void gru_mfma_kernel(
    const float* __restrict__ xpf, const float* __restrict__ xpb,
    const unsigned short* __restrict__ Upk0, const unsigned short* __restrict__ Upk1,
    const float* __restrict__ bb0, const float* __restrict__ bb1,
    const float* __restrict__ h0,
    unsigned short* __restrict__ yh, unsigned short* __restrict__ yl)
{
    __shared__ float h[16][272];    // padded stride (2-way max on A-build reads)
    __shared__ float g8[8][772];    // half-tile gate preacts

    const int dir = blockIdx.y;
    const float* xp = dir ? xpb : xpf;
    const unsigned short* Upk = dir ? Upk1 : Upk0;
    const float* b = dir ? bb1 : bb0;
    const int out_off = dir ? 256 : 0;

    const int tid  = threadIdx.x;
    const int lane = tid & 63;
    const int w    = tid >> 6;
    const int lrow = lane & 15;
    const int lk8  = (lane >> 4) * 8;
    const int r0   = blockIdx.x * 16;

    #pragma unroll
    for (int i = 0; i < 16; ++i)
        h[i][tid] = h0 ? h0[(size_t)(r0 + i) * 256 + tid] : 0.f;

    const float bz = b[768 + tid], br = b[768 + 256 + tid], bhv = b[768 + 512 + tid];
    __syncthreads();

    for (int t = 0; t < TT; ++t) {
        const int te = dir ? (TT - 1 - t) : t;

        // prefetch xp for rows 0-7 (consumed after the MFMA phase)
        float x1[24];
        #pragma unroll
        for (int i = 0; i < 8; ++i) {
            const float* xr_ = xp + ((size_t)(r0 + i) * TT + te) * 768 + tid;
            x1[i * 3 + 0] = xr_[0];
            x1[i * 3 + 1] = xr_[256];
            x1[i * 3 + 2] = xr_[512];
        }

        f32x4 acc[12];
        #pragma unroll
        for (int j = 0; j < 12; ++j) acc[j] = (f32x4){0.f, 0.f, 0.f, 0.f};

        bf16x8 bufA[12], bufB[12];
        load_group(Upk + ((size_t)(w * 12)) * 1024 + lane * 8, bufA);

        for (int kt = 0; kt < 8; ++kt) {
            const unsigned short* kbase = Upk + ((size_t)(kt * 48 + w * 12)) * 1024 + lane * 8;
            // issue group-1 loads before MFMAing group 0
            load_group(kbase + 6 * 1024, bufB);

            // build A fragment for this kt: h[lrow][kt*32+lk8..+8] -> hi/lo
            float4 a0 = *(const float4*)&h[lrow][kt * 32 + lk8];
            float4 a1 = *(const float4*)&h[lrow][kt * 32 + lk8 + 4];
            float av[8] = {a0.x, a0.y, a0.z, a0.w, a1.x, a1.y, a1.z, a1.w};
            bf16x8 ah, al;
            #pragma unroll
            for (int e = 0; e < 8; ++e) {
                unsigned short hi = f2bf(av[e]);
                ah[e] = (short)hi;
                al[e] = (short)f2bf(av[e] - bf2f(hi));
            }

            mfma_group(ah, al, bufA, &acc[0]);     // covers bufB loads
            if (kt + 1 < 8)
                load_group(kbase + 48 * 1024, bufA);   // next kt, group 0
            mfma_group(ah, al, bufB, &acc[6]);     // covers bufA loads
        }

        // prefetch xp for rows 8-15 (hides under half-1 epilogue)
        float x2[24];
        #pragma unroll
        for (int i = 0; i < 8; ++i) {
            const float* xr_ = xp + ((size_t)(r0 + 8 + i) * TT + te) * 768 + tid;
            x2[i * 3 + 0] = xr_[0];
            x2[i * 3 + 1] = xr_[256];
            x2[i * 3 + 2] = xr_[512];
        }

        // ---- half 1: rows 0-7 (acc rows live in lanes 0-31) ----
        if (lane < 32) {
            const int rowb = (lane >> 4) * 4;
            #pragma unroll
            for (int j = 0; j < 12; ++j) {
                const int col = w * 192 + j * 16 + lrow;
                #pragma unroll
                for (int r = 0; r < 4; ++r)
                    g8[rowb + r][col] = acc[j][r];
            }
        }
        __syncthreads();
        #pragma unroll
        for (int i = 0; i < 8; ++i) {
            float z  = 1.f / (1.f + expf(-(x1[i * 3 + 0] + g8[i][tid] + bz)));
            float r_ = 1.f / (1.f + expf(-(x1[i * 3 + 1] + g8[i][tid + 256] + br)));
            float hh = tanhf(x1[i * 3 + 2] + r_ * (g8[i][tid + 512] + bhv));
            float hn = z * h[i][tid] + (1.f - z) * hh;
            h[i][tid] = hn;
            const size_t yi = ((size_t)(r0 + i) * TT + te) * 512 + out_off + tid;
            unsigned short hb = f2bf(hn);
            yh[yi] = hb;
            yl[yi] = f2bf(hn - bf2f(hb));
        }
        __syncthreads();

        // ---- half 2: rows 8-15 (acc rows live in lanes 32-63) ----
        if (lane >= 32) {
            const int rowb = ((lane >> 4) - 2) * 4;
            #pragma unroll
            for (int j = 0; j < 12; ++j) {
                const int col = w * 192 + j * 16 + lrow;
                #pragma unroll
                for (int r = 0; r < 4; ++r)
                    g8[rowb + r][col] = acc[j][r];
            }
        }
        __syncthreads();
        #pragma unroll
        for (int i = 0; i < 8; ++i) {
            const int row = i + 8;
            float z  = 1.f / (1.f + expf(-(x2[i * 3 + 0] + g8[i][tid] + bz)));
            float r_ = 1.f / (1.f + expf(-(x2[i * 3 + 1] + g8[i][tid + 256] + br)));
            float hh = tanhf(x2[i * 3 + 2] + r_ * (g8[i][tid + 512] + bhv));
            float hn = z * h[row][tid] + (1.f - z) * hh;
            h[row][tid] = hn;
            const size_t yi = ((size_t)(r0 + row) * TT + te) * 512 + out_off + tid;
            unsigned short hb = f2bf(hn);
            yh[yi] = hb;
            yl[yi] = f2bf(hn - bf2f(hb));
        }
        __syncthreads();
    }
}

// ============================================================================
// tail: per batch row (64 lanes): score from H, softmax over T, att write,
// ctx = sum w_t * Y (Y reconstructed hi+lo).
// ============================================================================
__global__ __launch_bounds__(64) void tail_kernel(
    const float* __restrict__ H, const unsigned short* __restrict__ Yh,
    const unsigned short* __restrict__ Yl,
    const float* __restrict__ V, const float* __restrict__ bV,
    float* __restrict__ ctx, float* __restrict__ att)
{
    const int b = blockIdx.x;
    const int lane = threadIdx.x;

    float sc[TT];
    #pragma unroll
    for (int t = 0; t < TT; ++t) {
        const float* Hp = H + ((size_t)b * TT + t) * 512;
        float s = 0.f;
        #pragma unroll
        for (int j = 0; j < 8; ++j) {
            int cix = lane + j * 64;
            s = fmaf(tanhf(Hp[cix]), V[cix], s);
        }
        #pragma unroll
        for (int off = 32; off > 0; off >>= 1) s += __shfl_xor(s, off);
        sc[t] = s + bV[0];
    }
    float m = sc[0];
    #pragma unroll
    for (int t = 1; t < TT; ++t) m = fmaxf(m, sc[t]);
    float sum = 0.f;
    float wt[TT];
    #pragma unroll
    for (int t = 0; t < TT; ++t) { wt[t] = expf(sc[t] - m); sum += wt[t]; }
    const float inv = 1.f / sum;
    #pragma unroll
    for (int t = 0; t < TT; ++t) {
        wt[t] *= inv;
        if (lane == t) att[(size_t)b * TT + t] = wt[t];
    }
    #pragma unroll
    for (int j = 0; j < 8; ++j) {
        int cix = lane + j * 64;
        float a = 0.f;
        #pragma unroll
        for (int t = 0; t < TT; ++t) {
            size_t yi = ((size_t)b * TT + t) * 512 + cix;
            a = fmaf(wt[t], bf2f(Yh[yi]) + bf2f(Yl[yi]), a);
        }
        ctx[(size_t)b * 512 + cix] = a;
    }
}

// ============================================================================
// fused FC1(relu) + FC2 -> logits [rows,2] (unchanged)
// ============================================================================
__global__ __launch_bounds__(256) void fc_kernel(
    const float* __restrict__ ctx, const float* __restrict__ W1, const float* __restrict__ b1,
    const float* __restrict__ W2, const float* __restrict__ b2,
    float* __restrict__ logits)
{
    __shared__ float clds[16][512];
    const int tid = threadIdx.x;
    const int r0 = blockIdx.x * 16;
    for (int idx = tid; idx < 16 * 512; idx += 256)
        clds[idx >> 9][idx & 511] = ctx[(size_t)r0 * 512 + idx];
    __syncthreads();

    float acc0[16], acc1[16];
    #pragma unroll
    for (int i = 0; i < 16; ++i) { acc0[i] = 0.f; acc1[i] = 0.f; }

    for (int k = 0; k < 512; k += 8) {
        float w[8][2];
        #pragma unroll
        for (int kk = 0; kk < 8; ++kk) {
            const float* Wr = W1 + (size_t)(k + kk) * 512;
            w[kk][0] = Wr[tid];
            w[kk][1] = Wr[tid + 256];
        }
        #pragma unroll
        for (int i = 0; i < 16; ++i) {
            float4 y0 = *(const float4*)&clds[i][k];
            float4 y1 = *(const float4*)&clds[i][k + 4];
            float yv[8] = {y0.x, y0.y, y0.z, y0.w, y1.x, y1.y, y1.z, y1.w};
            float s0 = acc0[i], s1 = acc1[i];
            #pragma unroll
            for (int kk = 0; kk < 8; ++kk) {
                s0 = fmaf(yv[kk], w[kk][0], s0);
                s1 = fmaf(yv[kk], w[kk][1], s1);
            }
            acc0[i] = s0; acc1[i] = s1;
        }
    }
    const float w2a0 = W2[(size_t)tid * 2],         w2a1 = W2[(size_t)tid * 2 + 1];
    const float w2b0 = W2[(size_t)(tid + 256) * 2], w2b1 = W2[(size_t)(tid + 256) * 2 + 1];
    const float c0 = b1[tid], c1 = b1[tid + 256];
    __syncthreads();
    #pragma unroll
    for (int i = 0; i < 16; ++i) {
        float h0v = fmaxf(acc0[i] + c0, 0.f);
        float h1v = fmaxf(acc1[i] + c1, 0.f);
        clds[i][tid * 2]     = fmaf(h0v, w2a0, h1v * w2b0);
        clds[i][tid * 2 + 1] = fmaf(h0v, w2a1, h1v * w2b1);
    }
    __syncthreads();
    const int wave = tid >> 6, lane = tid & 63;
    for (int i = wave * 4; i < wave * 4 + 4; ++i) {
        float px = clds[i][lane * 2]     + clds[i][(lane + 64) * 2]     + clds[i][(lane + 128) * 2]     + clds[i][(lane + 192) * 2];
        float py = clds[i][lane * 2 + 1] + clds[i][(lane + 64) * 2 + 1] + clds[i][(lane + 128) * 2 + 1] + clds[i][(lane + 192) * 2 + 1];
        #pragma unroll
        for (int off = 32; off > 0; off >>= 1) { px += __shfl_down(px, off); py += __shfl_down(py, off); }
        if (lane == 0) {
            logits[(size_t)(r0 + i) * 2]     = px + b2[0];
            logits[(size_t)(r0 + i) * 2 + 1] = py + b2[1];
        }
    }
}

// ============================================================================
extern "C" void kernel_launch(void* const* d_in, const int* in_sizes, int n_in,
                              void* d_out, int out_size, void* d_ws, size_t ws_size,
                              hipStream_t stream)
{
    const float* peptide = (const float*)d_in[0];
    const float* hidden  = (const float*)d_in[1];
    const float* gW[6] = { (const float*)d_in[2],  (const float*)d_in[5],
                           (const float*)d_in[8],  (const float*)d_in[11],
                           (const float*)d_in[14], (const float*)d_in[17] };
    const float* gU[6] = { (const float*)d_in[3],  (const float*)d_in[6],
                           (const float*)d_in[9],  (const float*)d_in[12],
                           (const float*)d_in[15], (const float*)d_in[18] };
    const float* gB[6] = { (const float*)d_in[4],  (const float*)d_in[7],
                           (const float*)d_in[10], (const float*)d_in[13],
                           (const float*)d_in[16], (const float*)d_in[19] };
    const float* att_W1 = (const float*)d_in[20];
    const float* att_b1 = (const float*)d_in[21];
    const float* att_V  = (const float*)d_in[22];
    const float* att_bV = (const float*)d_in[23];
    const float* fc1_W = (const float*)d_in[24];
    const float* fc1_b = (const float*)d_in[25];
    const float* fc2_W = (const float*)d_in[26];
    const float* fc2_b = (const float*)d_in[27];

    float* out = (float*)d_out;   // [0,8192) logits, [8192,45056) attention weights

    // Workspace per chunk: xpf + xpb f32, pep-bf16 region (y hi/lo aliases it
    // after the peptide is dead), W hi/lo (7 jobs), Upk (6 packed U).
    const size_t WJOB = 442368;
    const size_t UJOB = 393216;
    int NC = 1;
    size_t CB = 4096;
    for (; NC <= 32; NC *= 2) {
        CB = 4096 / NC;
        size_t bytes = 2 * (size_t)CB * TT * 768 * 4
                     + 2 * (size_t)CB * TT * 576 * 2
                     + 2 * 7 * WJOB * 2 + 6 * UJOB * 2;
        if (bytes <= ws_size) break;
    }
    if (NC > 32) { NC = 32; CB = 128; }

    char* ws = (char*)d_ws;
    float* xpf = (float*)ws;                                  ws += (size_t)CB * TT * 768 * 4;
    float* xpb = (float*)ws;                                  ws += (size_t)CB * TT * 768 * 4;
    unsigned short* Aph = (unsigned short*)ws;                // pep region (85MB @CB=4096)
    unsigned short* Apl = Aph + (size_t)CB * TT * 576;
    unsigned short* yh  = Aph;                                // y aliases pep (pep dead after L1 projm)
    unsigned short* yl  = yh + (size_t)CB * TT * 512;
    ws += 2 * (size_t)CB * TT * 576 * 2;
    unsigned short* Wh  = (unsigned short*)ws;                ws += 7 * WJOB * 2;
    unsigned short* Wl  = (unsigned short*)ws;                ws += 7 * WJOB * 2;
    unsigned short* Upk = (unsigned short*)ws;
    float* H   = xpf;     // attention preact (xpf dead after layer-3 gru)
    float* ctx = xpb;     // ctx (xpb dead after layer-3 gru)

    const int M = (int)CB * TT;
    dim3 pb(256), pg768(6, M / 128, 2), pg512(4, M / 128, 1);
    dim3 gb(256), gg((unsigned)CB / 16, 2);
    dim3 cab(256);

    // ---- one-shot weight prep (13 jobs fused) ----
    PrepPtrs pp;
    for (int i = 0; i < 6; ++i) { pp.w[i] = gW[i]; pp.u[i] = gU[i]; }
    pp.w[6] = att_W1;
    prep_kernel<<<dim3(1728, 13), cab, 0, stream>>>(pp, Wh, Wl, Upk);

    for (int c = 0; c < NC; ++c) {
        const float* pep_c = peptide + (size_t)c * CB * TT * 553;
        const float* hid_c = hidden + (size_t)c * CB * 256;
        float* logits_c = out + (size_t)c * CB * 2;
        float* att_c    = out + 8192 + (size_t)c * CB * TT;

        // ---- layer 1 (Kp=576, h0 = hidden) ----
        cvta_kernel<<<dim3(2048), cab, 0, stream>>>(pep_c, Aph, Apl, 553, 576, (unsigned)M * 576u);
        projm_kernel<<<pg768, pb, 0, stream>>>(Aph, Apl,
            Wh + 0 * WJOB, Wl + 0 * WJOB, gB[0], xpf,
            Wh + 1 * WJOB, Wl + 1 * WJOB, gB[1], xpb, 576, 768);
        gru_mfma_kernel<<<gg, gb, 0, stream>>>(xpf, xpb, Upk + 0 * UJOB, Upk + 1 * UJOB,
                                               gB[0], gB[1], hid_c, yh, yl);

        // ---- layer 2 (Kp=512, h0 = 0) ----
        projm_kernel<<<pg768, pb, 0, stream>>>(yh, yl,
            Wh + 2 * WJOB, Wl + 2 * WJOB, gB[2], xpf,
            Wh + 3 * WJOB, Wl + 3 * WJOB, gB[3], xpb, 512, 768);
        gru_mfma_kernel<<<gg, gb, 0, stream>>>(xpf, xpb, Upk + 2 * UJOB, Upk + 3 * UJOB,
                                               gB[2], gB[3], nullptr, yh, yl);

        // ---- layer 3 ----
        projm_kernel<<<pg768, pb, 0, stream>>>(yh, yl,
            Wh + 4 * WJOB, Wl + 4 * WJOB, gB[4], xpf,
            Wh + 5 * WJOB, Wl + 5 * WJOB, gB[5], xpb, 512, 768);
        gru_mfma_kernel<<<gg, gb, 0, stream>>>(xpf, xpb, Upk + 4 * UJOB, Upk + 5 * UJOB,
                                               gB[4], gB[5], nullptr, yh, yl);

        // ---- attention: H = Y@W1 + b1 (MFMA), fused tail, head ----
        projm_kernel<<<pg512, pb, 0, stream>>>(yh, yl,
            Wh + 6 * WJOB, Wl + 6 * WJOB, att_b1, H,
            Wh + 6 * WJOB, Wl + 6 * WJOB, att_b1, H, 512, 512);
        tail_kernel<<<dim3((unsigned)CB), dim3(64), 0, stream>>>(H, yh, yl, att_V, att_bV, ctx, att_c);
        fc_kernel<<<dim3((unsigned)CB / 16), dim3(256), 0, stream>>>(ctx, fc1_W, fc1_b, fc2_W, fc2_b, logits_c);
    }
}